// Round 1
// baseline (1422.181 us; speedup 1.0000x reference)
//
#include <hip/hip_runtime.h>
#include <hip/hip_bf16.h>

#define EMB 128
#define EDGE 32
#define STEPS 3
#define TM 64

__device__ __forceinline__ float lrelu(float v) { return v > 0.0f ? v : 0.01f * v; }

// ---------------- CSR build ----------------
__global__ void k_hist(const int* __restrict__ dst, int E, int* __restrict__ deg) {
    int e = blockIdx.x * 256 + threadIdx.x;
    if (e < E) atomicAdd(&deg[dst[e]], 1);
}

__global__ void k_scan1(const int* __restrict__ deg, int N, int* __restrict__ rowptr,
                        int* __restrict__ bsums) {
    __shared__ int s[256];
    int t = threadIdx.x;
    int i = blockIdx.x * 256 + t;
    int v = (i < N) ? deg[i] : 0;
    s[t] = v;
    __syncthreads();
#pragma unroll
    for (int off = 1; off < 256; off <<= 1) {
        int x = (t >= off) ? s[t - off] : 0;
        __syncthreads();
        s[t] += x;
        __syncthreads();
    }
    if (i < N) rowptr[i] = s[t] - v;
    if (t == 255) bsums[blockIdx.x] = s[255];
}

__global__ void k_scan2(int* __restrict__ bsums, int NB) {
    __shared__ int s[256];
    __shared__ int carry;
    int t = threadIdx.x;
    if (t == 0) carry = 0;
    __syncthreads();
    for (int base = 0; base < NB; base += 256) {
        int i = base + t;
        int v = (i < NB) ? bsums[i] : 0;
        s[t] = v;
        __syncthreads();
#pragma unroll
        for (int off = 1; off < 256; off <<= 1) {
            int x = (t >= off) ? s[t - off] : 0;
            __syncthreads();
            s[t] += x;
            __syncthreads();
        }
        int excl = s[t] - v + carry;
        if (i < NB) bsums[i] = excl;
        int tot = s[255];
        __syncthreads();
        if (t == 0) carry += tot;
        __syncthreads();
    }
}

__global__ void k_scan3(int* __restrict__ rowptr, const int* __restrict__ bsums, int N, int E) {
    int i = blockIdx.x * 256 + threadIdx.x;
    if (i < N) rowptr[i] += bsums[i >> 8];
    if (i == 0) rowptr[N] = E;
}

__global__ void k_fill(const int* __restrict__ src, const int* __restrict__ dst, int E,
                       int* __restrict__ cursor, int* __restrict__ slot_src,
                       int* __restrict__ slot_eid) {
    int e = blockIdx.x * 256 + threadIdx.x;
    if (e < E) {
        int d = dst[e];
        int p = atomicAdd(&cursor[d], 1);
        slot_src[p] = src[e];
        slot_eid[p] = e;
    }
}

__global__ void k_gstart(const int* __restrict__ batch, int N, int G, int* __restrict__ gstart) {
    int g = blockIdx.x * blockDim.x + threadIdx.x;
    if (g > G) return;
    int lo = 0, hi = N;
    while (lo < hi) {
        int mid = (lo + hi) >> 1;
        if (batch[mid] < g) lo = mid + 1; else hi = mid;
    }
    gstart[g] = lo;
}

// ---------------- GEMM core: 64-row tile, 128 cols, K=128 ----------------
__device__ __forceinline__ void gemm_stage_A(const float* __restrict__ A, int row0, int N,
                                             float* As) {
    int tid = threadIdx.x;
#pragma unroll
    for (int i = 0; i < 8; ++i) {
        int idx = tid + i * 256;       // float4 index into 64x128 tile
        int r = idx >> 5;              // 32 float4 per row
        int c4 = idx & 31;
        float4 v = make_float4(0.f, 0.f, 0.f, 0.f);
        if (row0 + r < N) v = ((const float4*)(A + (size_t)(row0 + r) * EMB))[c4];
        ((float4*)As)[idx] = v;
    }
}

__device__ __forceinline__ void gemm_mainloop(const float* __restrict__ W, const float* As,
                                              float* Ws, float4 acc[8]) {
    int tid = threadIdx.x;
    int tx = tid & 31, ty = tid >> 5;
    for (int kc = 0; kc < 2; ++kc) {
        __syncthreads();
#pragma unroll
        for (int i = 0; i < 8; ++i) {
            int idx = tid + i * 256;
            int r = idx >> 5, c4 = idx & 31;
            ((float4*)Ws)[idx] = ((const float4*)(W + (size_t)(kc * 64 + r) * EMB))[c4];
        }
        __syncthreads();
#pragma unroll 4
        for (int k0 = 0; k0 < 64; k0 += 4) {
            float4 w0 = ((const float4*)Ws)[(k0 + 0) * 32 + tx];
            float4 w1 = ((const float4*)Ws)[(k0 + 1) * 32 + tx];
            float4 w2 = ((const float4*)Ws)[(k0 + 2) * 32 + tx];
            float4 w3 = ((const float4*)Ws)[(k0 + 3) * 32 + tx];
            int kidx = (kc * 64 + k0) >> 2;
#pragma unroll
            for (int i = 0; i < 8; ++i) {
                float4 a = ((const float4*)As)[(ty * 8 + i) * 32 + kidx];
                acc[i].x = fmaf(a.x, w0.x, fmaf(a.y, w1.x, fmaf(a.z, w2.x, fmaf(a.w, w3.x, acc[i].x))));
                acc[i].y = fmaf(a.x, w0.y, fmaf(a.y, w1.y, fmaf(a.z, w2.y, fmaf(a.w, w3.y, acc[i].y))));
                acc[i].z = fmaf(a.x, w0.z, fmaf(a.y, w1.z, fmaf(a.z, w2.z, fmaf(a.w, w3.z, acc[i].z))));
                acc[i].w = fmaf(a.x, w0.w, fmaf(a.y, w1.w, fmaf(a.z, w2.w, fmaf(a.w, w3.w, acc[i].w))));
            }
        }
    }
}

// h = x @ Wm_x + bm
__global__ __launch_bounds__(256, 2) void k_gemm_bias(const float* __restrict__ A,
                                                      const float* __restrict__ W,
                                                      const float* __restrict__ bias,
                                                      float* __restrict__ C, int N) {
    __shared__ float As[TM * EMB];
    __shared__ float Ws[64 * EMB];
    float4 acc[8] = {};
    int row0 = blockIdx.x * TM;
    gemm_stage_A(A, row0, N, As);
    gemm_mainloop(W, As, Ws, acc);
    int tx = threadIdx.x & 31, ty = threadIdx.x >> 5;
    float4 b = ((const float4*)bias)[tx];
#pragma unroll
    for (int i = 0; i < 8; ++i) {
        int r = row0 + ty * 8 + i;
        if (r < N) {
            float4 o;
            o.x = acc[i].x + b.x; o.y = acc[i].y + b.y;
            o.z = acc[i].z + b.z; o.w = acc[i].w + b.w;
            ((float4*)(C + (size_t)r * EMB))[tx] = o;
        }
    }
}

// x_out = lrelu(x@Wa_x + agg@Wa_a + gb[batch]) + x
__global__ __launch_bounds__(256, 2) void k_gemm_node(const float* __restrict__ x,
                                                      const float* __restrict__ agg,
                                                      const float* __restrict__ Wa,
                                                      const float* __restrict__ gb,
                                                      const int* __restrict__ batch,
                                                      float* __restrict__ C, int N) {
    __shared__ float As[TM * EMB];
    __shared__ float Ws[64 * EMB];
    float4 acc[8] = {};
    int row0 = blockIdx.x * TM;
    gemm_stage_A(x, row0, N, As);
    gemm_mainloop(Wa, As, Ws, acc);            // rows 0..127 (x part)
    __syncthreads();
    gemm_stage_A(agg, row0, N, As);
    gemm_mainloop(Wa + 256 * EMB, As, Ws, acc); // rows 256..383 (agg part)
    int tx = threadIdx.x & 31, ty = threadIdx.x >> 5;
#pragma unroll
    for (int i = 0; i < 8; ++i) {
        int r = row0 + ty * 8 + i;
        if (r < N) {
            int g = batch[r];
            float4 b = ((const float4*)(gb + (size_t)g * EMB))[tx];
            float4 res = ((const float4*)(x + (size_t)r * EMB))[tx];
            float4 o;
            o.x = lrelu(acc[i].x + b.x) + res.x;
            o.y = lrelu(acc[i].y + b.y) + res.y;
            o.z = lrelu(acc[i].z + b.z) + res.z;
            o.w = lrelu(acc[i].w + b.w) + res.w;
            ((float4*)(C + (size_t)r * EMB))[tx] = o;
        }
    }
}

// featbuf = alpha * lrelu(x@Wfeat + bfeat)
__global__ __launch_bounds__(256, 2) void k_gemm_feat(const float* __restrict__ A,
                                                      const float* __restrict__ W,
                                                      const float* __restrict__ bias,
                                                      const float* __restrict__ gate,
                                                      const float* __restrict__ gmax,
                                                      const float* __restrict__ denom,
                                                      const int* __restrict__ batch,
                                                      float* __restrict__ C, int N) {
    __shared__ float As[TM * EMB];
    __shared__ float Ws[64 * EMB];
    float4 acc[8] = {};
    int row0 = blockIdx.x * TM;
    gemm_stage_A(A, row0, N, As);
    gemm_mainloop(W, As, Ws, acc);
    int tx = threadIdx.x & 31, ty = threadIdx.x >> 5;
    float4 b = ((const float4*)bias)[tx];
#pragma unroll
    for (int i = 0; i < 8; ++i) {
        int r = row0 + ty * 8 + i;
        if (r < N) {
            int g = batch[r];
            float alpha = __expf(gate[r] - gmax[g]) / denom[g];
            float4 o;
            o.x = alpha * lrelu(acc[i].x + b.x);
            o.y = alpha * lrelu(acc[i].y + b.y);
            o.z = alpha * lrelu(acc[i].z + b.z);
            o.w = alpha * lrelu(acc[i].w + b.w);
            ((float4*)(C + (size_t)r * EMB))[tx] = o;
        }
    }
}

// ---------------- fused edge message + segment-max (CSR, wave per node) ----------------
__global__ __launch_bounds__(256) void k_agg(const float* __restrict__ h,
                                             const float* __restrict__ ea,
                                             const float* __restrict__ Wme,
                                             const int* __restrict__ rowptr,
                                             const int* __restrict__ slot_src,
                                             const int* __restrict__ slot_eid,
                                             float* __restrict__ agg, int N, int nwaves) {
    int wv = blockIdx.x * 4 + (threadIdx.x >> 6);
    int lane = threadIdx.x & 63;
    // Wm_e fragment for this lane's 2 channels, held in registers (64 VGPRs)
    float2 w2[32];
#pragma unroll
    for (int k = 0; k < 32; ++k) w2[k] = *(const float2*)(Wme + k * EMB + lane * 2);
    for (int n = wv; n < N; n += nwaves) {
        int r0 = rowptr[n], r1 = rowptr[n + 1];
        float2 vmax = make_float2(-__builtin_inff(), -__builtin_inff());
        for (int p = r0; p < r1; ++p) {
            int src = __builtin_amdgcn_readfirstlane(slot_src[p]);
            int eid = __builtin_amdgcn_readfirstlane(slot_eid[p]);
            const float* eap = ea + (size_t)eid * EDGE;
            float2 acc = *(const float2*)(h + (size_t)src * EMB + lane * 2);
#pragma unroll
            for (int k = 0; k < 32; ++k) {
                float a = eap[k];
                acc.x = fmaf(a, w2[k].x, acc.x);
                acc.y = fmaf(a, w2[k].y, acc.y);
            }
            acc.x = lrelu(acc.x);
            acc.y = lrelu(acc.y);
            vmax.x = fmaxf(vmax.x, acc.x);
            vmax.y = fmaxf(vmax.y, acc.y);
        }
        if (r0 == r1) { vmax.x = 0.f; vmax.y = 0.f; }
        *(float2*)(agg + (size_t)n * EMB + lane * 2) = vmax;
    }
}

// ---------------- small per-graph kernels ----------------
// gb = xg @ Wa_g + ba   (G rows)
__global__ __launch_bounds__(128) void k_gb(const float* __restrict__ xg,
                                            const float* __restrict__ WaG,
                                            const float* __restrict__ ba,
                                            float* __restrict__ gb) {
    int g = blockIdx.x, c = threadIdx.x;
    __shared__ float row[EMB];
    row[c] = xg[(size_t)g * EMB + c];
    __syncthreads();
    float acc = ba[c];
#pragma unroll 8
    for (int k = 0; k < EMB; ++k) acc = fmaf(row[k], WaG[(size_t)k * EMB + c], acc);
    gb[(size_t)g * EMB + c] = acc;
}

// gate[n] = x[n] . wg + bg
__global__ __launch_bounds__(256) void k_gate(const float* __restrict__ x,
                                              const float* __restrict__ wg,
                                              const float* __restrict__ bg,
                                              float* __restrict__ gate, int N) {
    int n = blockIdx.x * 4 + (threadIdx.x >> 6);
    int lane = threadIdx.x & 63;
    if (n >= N) return;
    const float* xr = x + (size_t)n * EMB;
    float v = fmaf(xr[lane], wg[lane], xr[lane + 64] * wg[lane + 64]);
#pragma unroll
    for (int off = 32; off; off >>= 1) v += __shfl_xor(v, off, 64);
    if (lane == 0) gate[n] = v + bg[0];
}

// per-graph max + sum(exp)
__global__ __launch_bounds__(256) void k_gseg(const float* __restrict__ gate,
                                              const int* __restrict__ gstart,
                                              float* __restrict__ gmax,
                                              float* __restrict__ denom) {
    int g = blockIdx.x;
    int s0 = gstart[g], s1 = gstart[g + 1];
    __shared__ float red[256];
    int t = threadIdx.x;
    float mx = -__builtin_inff();
    for (int i = s0 + t; i < s1; i += 256) mx = fmaxf(mx, gate[i]);
    red[t] = mx;
    __syncthreads();
#pragma unroll
    for (int off = 128; off; off >>= 1) {
        if (t < off) red[t] = fmaxf(red[t], red[t + off]);
        __syncthreads();
    }
    float m = red[0];
    __syncthreads();
    float sum = 0.f;
    for (int i = s0 + t; i < s1; i += 256) sum += __expf(gate[i] - m);
    red[t] = sum;
    __syncthreads();
#pragma unroll
    for (int off = 128; off; off >>= 1) {
        if (t < off) red[t] += red[t + off];
        __syncthreads();
    }
    if (t == 0) {
        gmax[g] = (s1 > s0) ? m : 0.f;
        denom[g] = red[0];
    }
}

// pooled[g] = sum of featbuf rows in [gstart[g], gstart[g+1])
__global__ __launch_bounds__(128) void k_pool(const float* __restrict__ feat,
                                              const int* __restrict__ gstart,
                                              float* __restrict__ pooled) {
    int g = blockIdx.x, c = threadIdx.x;
    int s0 = gstart[g], s1 = gstart[g + 1];
    float s = 0.f;
    for (int i = s0; i < s1; ++i) s += feat[(size_t)i * EMB + c];
    pooled[(size_t)g * EMB + c] = s;
}

// xg_out = lrelu([pooled, xg] @ Wt + bt) + xg
__global__ __launch_bounds__(128) void k_xg(const float* __restrict__ pooled,
                                            const float* __restrict__ xg,
                                            const float* __restrict__ Wt,
                                            const float* __restrict__ bt,
                                            float* __restrict__ xg_out) {
    int g = blockIdx.x, c = threadIdx.x;
    __shared__ float row[256];
    row[c] = pooled[(size_t)g * EMB + c];
    row[c + 128] = xg[(size_t)g * EMB + c];
    __syncthreads();
    float acc = bt[c];
#pragma unroll 8
    for (int k = 0; k < 256; ++k) acc = fmaf(row[k], Wt[(size_t)k * EMB + c], acc);
    xg_out[(size_t)g * EMB + c] = lrelu(acc) + row[c + 128];
}

// ---------------- launch ----------------
extern "C" void kernel_launch(void* const* d_in, const int* in_sizes, int n_in,
                              void* d_out, int out_size, void* d_ws, size_t ws_size,
                              hipStream_t stream) {
    const float* x0    = (const float*)d_in[0];
    const float* ea    = (const float*)d_in[1];
    const float* Wm    = (const float*)d_in[2];
    const float* bm    = (const float*)d_in[3];
    const float* Wa    = (const float*)d_in[4];
    const float* ba    = (const float*)d_in[5];
    const float* Wgate = (const float*)d_in[6];
    const float* bgate = (const float*)d_in[7];
    const float* Wfeat = (const float*)d_in[8];
    const float* bfeat = (const float*)d_in[9];
    const float* Wt    = (const float*)d_in[10];
    const float* bt    = (const float*)d_in[11];
    const int*   eidx  = (const int*)d_in[12];   // [2,E]: src then dst
    const int*   batch = (const int*)d_in[13];

    int N = in_sizes[0] / EMB;
    int E = in_sizes[1] / EDGE;
    int G = in_sizes[15];                        // data_lens has shape (G,)

    // workspace carve (256B aligned)
    char* w = (char*)d_ws;
    auto alloc = [&](size_t bytes) {
        char* p = w;
        w += (bytes + 255) & ~(size_t)255;
        return p;
    };
    float* hbuf   = (float*)alloc((size_t)N * EMB * 4);  // also featbuf
    float* agg    = (float*)alloc((size_t)N * EMB * 4);
    float* xa     = (float*)alloc((size_t)N * EMB * 4);
    float* xb     = (float*)alloc((size_t)N * EMB * 4);
    float* gate   = (float*)alloc((size_t)N * 4);
    float* gb     = (float*)alloc((size_t)G * EMB * 4);
    float* pooled = (float*)alloc((size_t)G * EMB * 4);
    float* gmax   = (float*)alloc((size_t)G * 4);
    float* denom  = (float*)alloc((size_t)G * 4);
    float* xg_a   = (float*)alloc((size_t)G * EMB * 4);
    float* xg_b   = (float*)alloc((size_t)G * EMB * 4);
    int* deg      = (int*)alloc((size_t)N * 4);
    int* rowptr   = (int*)alloc((size_t)(N + 1) * 4);
    int* cursor   = (int*)alloc((size_t)N * 4);
    int* slot_src = (int*)alloc((size_t)E * 4);
    int* slot_eid = (int*)alloc((size_t)E * 4);
    int* gstart   = (int*)alloc((size_t)(G + 1) * 4);
    int* bsums    = (int*)alloc(1024 * 4);

    const int* esrc = eidx;
    const int* edst = eidx + E;

    int ebl = (E + 255) / 256;
    int NB  = (N + 255) / 256;

    // CSR build (per launch; inputs re-poisoned each call)
    hipMemsetAsync(deg, 0, (size_t)N * 4, stream);
    k_hist<<<ebl, 256, 0, stream>>>(edst, E, deg);
    k_scan1<<<NB, 256, 0, stream>>>(deg, N, rowptr, bsums);
    k_scan2<<<1, 256, 0, stream>>>(bsums, NB);
    k_scan3<<<NB, 256, 0, stream>>>(rowptr, bsums, N, E);
    hipMemcpyAsync(cursor, rowptr, (size_t)N * 4, hipMemcpyDeviceToDevice, stream);
    k_fill<<<ebl, 256, 0, stream>>>(esrc, edst, E, cursor, slot_src, slot_eid);
    k_gstart<<<(G + 256) / 256, 256, 0, stream>>>(batch, N, G, gstart);
    hipMemsetAsync(xg_a, 0, (size_t)G * EMB * 4, stream);

    int gemm_blocks = (N + TM - 1) / TM;
    int gate_blocks = (N + 3) / 4;
    const int AGG_BLOCKS = 512;
    int agg_waves = AGG_BLOCKS * 4;

    const float* x_in = x0;
    float* x_chain[STEPS] = {xa, xb, (float*)d_out};
    float* xg_cur = xg_a;
    float* xg_nxt = xg_b;

    for (int s = 0; s < STEPS; ++s) {
        const float* Wm_s = Wm + (size_t)s * 160 * EMB;
        const float* Wa_s = Wa + (size_t)s * 384 * EMB;
        float* x_out = x_chain[s];

        // h = x @ Wm_x + bm
        k_gemm_bias<<<gemm_blocks, 256, 0, stream>>>(x_in, Wm_s, bm + s * EMB, hbuf, N);
        // agg = segment_max(lrelu(h[src] + ea@Wm_e), dst)
        k_agg<<<AGG_BLOCKS, 256, 0, stream>>>(hbuf, ea, Wm_s + 128 * EMB, rowptr,
                                              slot_src, slot_eid, agg, N, agg_waves);
        // gb = xg @ Wa_g + ba
        k_gb<<<G, 128, 0, stream>>>(xg_cur, Wa_s + 128 * EMB, ba + s * EMB, gb);
        // x_out = lrelu(x@Wa_x + agg@Wa_a + gb[batch]) + x
        k_gemm_node<<<gemm_blocks, 256, 0, stream>>>(x_in, agg, Wa_s, gb, batch, x_out, N);
        // gate
        k_gate<<<gate_blocks, 256, 0, stream>>>(x_out, Wgate + s * EMB, bgate + s, gate, N);
        k_gseg<<<G, 256, 0, stream>>>(gate, gstart, gmax, denom);
        // featbuf = alpha * lrelu(x_out@Wfeat + bfeat)   (featbuf aliases hbuf)
        k_gemm_feat<<<gemm_blocks, 256, 0, stream>>>(x_out, Wfeat + (size_t)s * EMB * EMB,
                                                     bfeat + s * EMB, gate, gmax, denom,
                                                     batch, hbuf, N);
        k_pool<<<G, 128, 0, stream>>>(hbuf, gstart, pooled);
        // xg update
        k_xg<<<G, 128, 0, stream>>>(pooled, xg_cur, Wt + (size_t)s * 256 * EMB,
                                    bt + s * EMB, xg_nxt);

        x_in = x_out;
        float* tmp = xg_cur; xg_cur = xg_nxt; xg_nxt = tmp;
    }

    // final xg -> tail of d_out
    hipMemcpyAsync((float*)d_out + (size_t)N * EMB, xg_cur, (size_t)G * EMB * 4,
                   hipMemcpyDeviceToDevice, stream);
}

// Round 2
// 1069.619 us; speedup vs baseline: 1.3296x; 1.3296x over previous
//
#include <hip/hip_runtime.h>
#include <hip/hip_bf16.h>

#define EMB 128
#define EDGE 32
#define STEPS 3
#define TM 64

__device__ __forceinline__ float lrelu(float v) { return v > 0.0f ? v : 0.01f * v; }

// ---------------- CSR build ----------------
__global__ void k_hist(const int* __restrict__ dst, int E, int* __restrict__ deg) {
    int e = blockIdx.x * 256 + threadIdx.x;
    if (e < E) atomicAdd(&deg[dst[e]], 1);
}

__global__ void k_scan1(const int* __restrict__ deg, int N, int* __restrict__ rowptr,
                        int* __restrict__ bsums) {
    __shared__ int s[256];
    int t = threadIdx.x;
    int i = blockIdx.x * 256 + t;
    int v = (i < N) ? deg[i] : 0;
    s[t] = v;
    __syncthreads();
#pragma unroll
    for (int off = 1; off < 256; off <<= 1) {
        int x = (t >= off) ? s[t - off] : 0;
        __syncthreads();
        s[t] += x;
        __syncthreads();
    }
    if (i < N) rowptr[i] = s[t] - v;
    if (t == 255) bsums[blockIdx.x] = s[255];
}

__global__ void k_scan2(int* __restrict__ bsums, int NB) {
    __shared__ int s[256];
    __shared__ int carry;
    int t = threadIdx.x;
    if (t == 0) carry = 0;
    __syncthreads();
    for (int base = 0; base < NB; base += 256) {
        int i = base + t;
        int v = (i < NB) ? bsums[i] : 0;
        s[t] = v;
        __syncthreads();
#pragma unroll
        for (int off = 1; off < 256; off <<= 1) {
            int x = (t >= off) ? s[t - off] : 0;
            __syncthreads();
            s[t] += x;
            __syncthreads();
        }
        int excl = s[t] - v + carry;
        if (i < NB) bsums[i] = excl;
        int tot = s[255];
        __syncthreads();
        if (t == 0) carry += tot;
        __syncthreads();
    }
}

__global__ void k_scan3(int* __restrict__ rowptr, const int* __restrict__ bsums, int N, int E) {
    int i = blockIdx.x * 256 + threadIdx.x;
    if (i < N) rowptr[i] += bsums[i >> 8];
    if (i == 0) rowptr[N] = E;
}

__global__ void k_fill(const int* __restrict__ src, const int* __restrict__ dst, int E,
                       int* __restrict__ cursor, int* __restrict__ slot_src,
                       int* __restrict__ slot_eid) {
    int e = blockIdx.x * 256 + threadIdx.x;
    if (e < E) {
        int d = dst[e];
        int p = atomicAdd(&cursor[d], 1);
        slot_src[p] = src[e];
        slot_eid[p] = e;
    }
}

__global__ void k_gstart(const int* __restrict__ batch, int N, int G, int* __restrict__ gstart) {
    int g = blockIdx.x * blockDim.x + threadIdx.x;
    if (g > G) return;
    int lo = 0, hi = N;
    while (lo < hi) {
        int mid = (lo + hi) >> 1;
        if (batch[mid] < g) lo = mid + 1; else hi = mid;
    }
    gstart[g] = lo;
}

// ---------------- GEMM core: 64-row tile, 128 cols, K=128 ----------------
__device__ __forceinline__ void gemm_stage_A(const float* __restrict__ A, int row0, int N,
                                             float* As) {
    int tid = threadIdx.x;
#pragma unroll
    for (int i = 0; i < 8; ++i) {
        int idx = tid + i * 256;       // float4 index into 64x128 tile
        int r = idx >> 5;              // 32 float4 per row
        int c4 = idx & 31;
        float4 v = make_float4(0.f, 0.f, 0.f, 0.f);
        if (row0 + r < N) v = ((const float4*)(A + (size_t)(row0 + r) * EMB))[c4];
        ((float4*)As)[idx] = v;
    }
}

__device__ __forceinline__ void gemm_mainloop(const float* __restrict__ W, const float* As,
                                              float* Ws, float4 acc[8]) {
    int tid = threadIdx.x;
    int tx = tid & 31, ty = tid >> 5;
    for (int kc = 0; kc < 2; ++kc) {
        __syncthreads();
#pragma unroll
        for (int i = 0; i < 8; ++i) {
            int idx = tid + i * 256;
            ((float4*)Ws)[idx] = ((const float4*)(W + (size_t)(kc * 64) * EMB))[idx];
        }
        __syncthreads();
#pragma unroll 4
        for (int k0 = 0; k0 < 64; k0 += 4) {
            float4 w0 = ((const float4*)Ws)[(k0 + 0) * 32 + tx];
            float4 w1 = ((const float4*)Ws)[(k0 + 1) * 32 + tx];
            float4 w2 = ((const float4*)Ws)[(k0 + 2) * 32 + tx];
            float4 w3 = ((const float4*)Ws)[(k0 + 3) * 32 + tx];
            int kidx = (kc * 64 + k0) >> 2;
#pragma unroll
            for (int i = 0; i < 8; ++i) {
                float4 a = ((const float4*)As)[(ty * 8 + i) * 32 + kidx];
                acc[i].x = fmaf(a.x, w0.x, fmaf(a.y, w1.x, fmaf(a.z, w2.x, fmaf(a.w, w3.x, acc[i].x))));
                acc[i].y = fmaf(a.x, w0.y, fmaf(a.y, w1.y, fmaf(a.z, w2.y, fmaf(a.w, w3.y, acc[i].y))));
                acc[i].z = fmaf(a.x, w0.z, fmaf(a.y, w1.z, fmaf(a.z, w2.z, fmaf(a.w, w3.z, acc[i].z))));
                acc[i].w = fmaf(a.x, w0.w, fmaf(a.y, w1.w, fmaf(a.z, w2.w, fmaf(a.w, w3.w, acc[i].w))));
            }
        }
    }
}

// h = x @ Wm_x + bm
__global__ __launch_bounds__(256, 2) void k_gemm_bias(const float* __restrict__ A,
                                                      const float* __restrict__ W,
                                                      const float* __restrict__ bias,
                                                      float* __restrict__ C, int N) {
    __shared__ float As[TM * EMB];
    __shared__ float Ws[64 * EMB];
    float4 acc[8] = {};
    int row0 = blockIdx.x * TM;
    gemm_stage_A(A, row0, N, As);
    gemm_mainloop(W, As, Ws, acc);
    int tx = threadIdx.x & 31, ty = threadIdx.x >> 5;
    float4 b = ((const float4*)bias)[tx];
#pragma unroll
    for (int i = 0; i < 8; ++i) {
        int r = row0 + ty * 8 + i;
        if (r < N) {
            float4 o;
            o.x = acc[i].x + b.x; o.y = acc[i].y + b.y;
            o.z = acc[i].z + b.z; o.w = acc[i].w + b.w;
            ((float4*)(C + (size_t)r * EMB))[tx] = o;
        }
    }
}

// x_out = lrelu(x@Wa_x + agg@Wa_a + gb[batch]) + x
__global__ __launch_bounds__(256, 2) void k_gemm_node(const float* __restrict__ x,
                                                      const float* __restrict__ agg,
                                                      const float* __restrict__ Wa,
                                                      const float* __restrict__ gb,
                                                      const int* __restrict__ batch,
                                                      float* __restrict__ C, int N) {
    __shared__ float As[TM * EMB];
    __shared__ float Ws[64 * EMB];
    float4 acc[8] = {};
    int row0 = blockIdx.x * TM;
    gemm_stage_A(x, row0, N, As);
    gemm_mainloop(Wa, As, Ws, acc);            // rows 0..127 (x part)
    __syncthreads();
    gemm_stage_A(agg, row0, N, As);
    gemm_mainloop(Wa + 256 * EMB, As, Ws, acc); // rows 256..383 (agg part)
    int tx = threadIdx.x & 31, ty = threadIdx.x >> 5;
#pragma unroll
    for (int i = 0; i < 8; ++i) {
        int r = row0 + ty * 8 + i;
        if (r < N) {
            int g = batch[r];
            float4 b = ((const float4*)(gb + (size_t)g * EMB))[tx];
            float4 res = ((const float4*)(x + (size_t)r * EMB))[tx];
            float4 o;
            o.x = lrelu(acc[i].x + b.x) + res.x;
            o.y = lrelu(acc[i].y + b.y) + res.y;
            o.z = lrelu(acc[i].z + b.z) + res.z;
            o.w = lrelu(acc[i].w + b.w) + res.w;
            ((float4*)(C + (size_t)r * EMB))[tx] = o;
        }
    }
}

// featbuf = alpha * lrelu(x@Wfeat + bfeat)
__global__ __launch_bounds__(256, 2) void k_gemm_feat(const float* __restrict__ A,
                                                      const float* __restrict__ W,
                                                      const float* __restrict__ bias,
                                                      const float* __restrict__ gate,
                                                      const float* __restrict__ gmax,
                                                      const float* __restrict__ denom,
                                                      const int* __restrict__ batch,
                                                      float* __restrict__ C, int N) {
    __shared__ float As[TM * EMB];
    __shared__ float Ws[64 * EMB];
    float4 acc[8] = {};
    int row0 = blockIdx.x * TM;
    gemm_stage_A(A, row0, N, As);
    gemm_mainloop(W, As, Ws, acc);
    int tx = threadIdx.x & 31, ty = threadIdx.x >> 5;
    float4 b = ((const float4*)bias)[tx];
#pragma unroll
    for (int i = 0; i < 8; ++i) {
        int r = row0 + ty * 8 + i;
        if (r < N) {
            int g = batch[r];
            float alpha = __expf(gate[r] - gmax[g]) / denom[g];
            float4 o;
            o.x = alpha * lrelu(acc[i].x + b.x);
            o.y = alpha * lrelu(acc[i].y + b.y);
            o.z = alpha * lrelu(acc[i].z + b.z);
            o.w = alpha * lrelu(acc[i].w + b.w);
            ((float4*)(C + (size_t)r * EMB))[tx] = o;
        }
    }
}

// ---------------- fused edge message + segment-max ----------------
// ONE wave per node (exact grid, no grid-stride): keeps the 64-VGPR Wm_e
// fragment's live range short so the allocator keeps it register-resident
// (R1 showed VGPR_Count=44 -> it was being reloaded per edge -> latency-bound).
// Edge loop unrolled x2 with independent chains to break the 32-FMA dep chain.
__global__ __launch_bounds__(256) void k_agg(const float* __restrict__ h,
                                             const float* __restrict__ ea,
                                             const float* __restrict__ Wme,
                                             const int* __restrict__ rowptr,
                                             const int* __restrict__ slot_src,
                                             const int* __restrict__ slot_eid,
                                             float* __restrict__ agg, int N) {
    int n = blockIdx.x * 4 + (threadIdx.x >> 6);
    if (n >= N) return;
    int lane = threadIdx.x & 63;

    int r0 = rowptr[n], r1 = rowptr[n + 1];
    float2 outv;
    if (r0 == r1) {
        outv = make_float2(0.f, 0.f);
    } else {
        // Wm_e fragment for this lane's 2 channels: 64 VGPRs
        float2 w2[32];
#pragma unroll
        for (int k = 0; k < 32; ++k) w2[k] = *(const float2*)(Wme + k * EMB + lane * 2);

        float2 vmax0 = make_float2(-__builtin_inff(), -__builtin_inff());
        float2 vmax1 = make_float2(-__builtin_inff(), -__builtin_inff());
        int p = r0;
        for (; p + 1 < r1; p += 2) {
            int src0 = __builtin_amdgcn_readfirstlane(slot_src[p]);
            int eid0 = __builtin_amdgcn_readfirstlane(slot_eid[p]);
            int src1 = __builtin_amdgcn_readfirstlane(slot_src[p + 1]);
            int eid1 = __builtin_amdgcn_readfirstlane(slot_eid[p + 1]);
            const float* ea0 = ea + (size_t)eid0 * EDGE;
            const float* ea1 = ea + (size_t)eid1 * EDGE;
            float2 a0 = *(const float2*)(h + (size_t)src0 * EMB + lane * 2);
            float2 a1 = *(const float2*)(h + (size_t)src1 * EMB + lane * 2);
#pragma unroll
            for (int k = 0; k < 32; ++k) {
                float e0 = ea0[k], e1 = ea1[k];
                a0.x = fmaf(e0, w2[k].x, a0.x);
                a0.y = fmaf(e0, w2[k].y, a0.y);
                a1.x = fmaf(e1, w2[k].x, a1.x);
                a1.y = fmaf(e1, w2[k].y, a1.y);
            }
            vmax0.x = fmaxf(vmax0.x, lrelu(a0.x));
            vmax0.y = fmaxf(vmax0.y, lrelu(a0.y));
            vmax1.x = fmaxf(vmax1.x, lrelu(a1.x));
            vmax1.y = fmaxf(vmax1.y, lrelu(a1.y));
        }
        if (p < r1) {
            int src0 = __builtin_amdgcn_readfirstlane(slot_src[p]);
            int eid0 = __builtin_amdgcn_readfirstlane(slot_eid[p]);
            const float* ea0 = ea + (size_t)eid0 * EDGE;
            float2 a0 = *(const float2*)(h + (size_t)src0 * EMB + lane * 2);
#pragma unroll
            for (int k = 0; k < 32; ++k) {
                float e0 = ea0[k];
                a0.x = fmaf(e0, w2[k].x, a0.x);
                a0.y = fmaf(e0, w2[k].y, a0.y);
            }
            vmax0.x = fmaxf(vmax0.x, lrelu(a0.x));
            vmax0.y = fmaxf(vmax0.y, lrelu(a0.y));
        }
        outv.x = fmaxf(vmax0.x, vmax1.x);
        outv.y = fmaxf(vmax0.y, vmax1.y);
    }
    *(float2*)(agg + (size_t)n * EMB + lane * 2) = outv;
}

// ---------------- small per-graph kernels ----------------
// gb = xg @ Wa_g + ba   (G rows)
__global__ __launch_bounds__(128) void k_gb(const float* __restrict__ xg,
                                            const float* __restrict__ WaG,
                                            const float* __restrict__ ba,
                                            float* __restrict__ gb) {
    int g = blockIdx.x, c = threadIdx.x;
    __shared__ float row[EMB];
    row[c] = xg[(size_t)g * EMB + c];
    __syncthreads();
    float acc = ba[c];
#pragma unroll 8
    for (int k = 0; k < EMB; ++k) acc = fmaf(row[k], WaG[(size_t)k * EMB + c], acc);
    gb[(size_t)g * EMB + c] = acc;
}

// gate[n] = x[n] . wg + bg
__global__ __launch_bounds__(256) void k_gate(const float* __restrict__ x,
                                              const float* __restrict__ wg,
                                              const float* __restrict__ bg,
                                              float* __restrict__ gate, int N) {
    int n = blockIdx.x * 4 + (threadIdx.x >> 6);
    int lane = threadIdx.x & 63;
    if (n >= N) return;
    const float* xr = x + (size_t)n * EMB;
    float v = fmaf(xr[lane], wg[lane], xr[lane + 64] * wg[lane + 64]);
#pragma unroll
    for (int off = 32; off; off >>= 1) v += __shfl_xor(v, off, 64);
    if (lane == 0) gate[n] = v + bg[0];
}

// per-graph max + sum(exp)
__global__ __launch_bounds__(256) void k_gseg(const float* __restrict__ gate,
                                              const int* __restrict__ gstart,
                                              float* __restrict__ gmax,
                                              float* __restrict__ denom) {
    int g = blockIdx.x;
    int s0 = gstart[g], s1 = gstart[g + 1];
    __shared__ float red[256];
    int t = threadIdx.x;
    float mx = -__builtin_inff();
    for (int i = s0 + t; i < s1; i += 256) mx = fmaxf(mx, gate[i]);
    red[t] = mx;
    __syncthreads();
#pragma unroll
    for (int off = 128; off; off >>= 1) {
        if (t < off) red[t] = fmaxf(red[t], red[t + off]);
        __syncthreads();
    }
    float m = red[0];
    __syncthreads();
    float sum = 0.f;
    for (int i = s0 + t; i < s1; i += 256) sum += __expf(gate[i] - m);
    red[t] = sum;
    __syncthreads();
#pragma unroll
    for (int off = 128; off; off >>= 1) {
        if (t < off) red[t] += red[t + off];
        __syncthreads();
    }
    if (t == 0) {
        gmax[g] = (s1 > s0) ? m : 0.f;
        denom[g] = red[0];
    }
}

// pooled[g] = sum of featbuf rows in [gstart[g], gstart[g+1]) — 4 rows/iter
__global__ __launch_bounds__(512) void k_pool(const float* __restrict__ feat,
                                              const int* __restrict__ gstart,
                                              float* __restrict__ pooled) {
    int g = blockIdx.x;
    int c = threadIdx.x & 127;
    int r = threadIdx.x >> 7;   // 0..3
    int s0 = gstart[g], s1 = gstart[g + 1];
    float s = 0.f;
    for (int i = s0 + r; i < s1; i += 4) s += feat[(size_t)i * EMB + c];
    __shared__ float red[512];
    red[threadIdx.x] = s;
    __syncthreads();
    if (threadIdx.x < 256) red[threadIdx.x] += red[threadIdx.x + 256];
    __syncthreads();
    if (threadIdx.x < 128)
        pooled[(size_t)g * EMB + threadIdx.x] = red[threadIdx.x] + red[threadIdx.x + 128];
}

// xg_out = lrelu([pooled, xg] @ Wt + bt) + xg
__global__ __launch_bounds__(128) void k_xg(const float* __restrict__ pooled,
                                            const float* __restrict__ xg,
                                            const float* __restrict__ Wt,
                                            const float* __restrict__ bt,
                                            float* __restrict__ xg_out) {
    int g = blockIdx.x, c = threadIdx.x;
    __shared__ float row[256];
    row[c] = pooled[(size_t)g * EMB + c];
    row[c + 128] = xg[(size_t)g * EMB + c];
    __syncthreads();
    float acc = bt[c];
#pragma unroll 8
    for (int k = 0; k < 256; ++k) acc = fmaf(row[k], Wt[(size_t)k * EMB + c], acc);
    xg_out[(size_t)g * EMB + c] = lrelu(acc) + row[c + 128];
}

// ---------------- launch ----------------
extern "C" void kernel_launch(void* const* d_in, const int* in_sizes, int n_in,
                              void* d_out, int out_size, void* d_ws, size_t ws_size,
                              hipStream_t stream) {
    const float* x0    = (const float*)d_in[0];
    const float* ea    = (const float*)d_in[1];
    const float* Wm    = (const float*)d_in[2];
    const float* bm    = (const float*)d_in[3];
    const float* Wa    = (const float*)d_in[4];
    const float* ba    = (const float*)d_in[5];
    const float* Wgate = (const float*)d_in[6];
    const float* bgate = (const float*)d_in[7];
    const float* Wfeat = (const float*)d_in[8];
    const float* bfeat = (const float*)d_in[9];
    const float* Wt    = (const float*)d_in[10];
    const float* bt    = (const float*)d_in[11];
    const int*   eidx  = (const int*)d_in[12];   // [2,E]: src then dst
    const int*   batch = (const int*)d_in[13];

    int N = in_sizes[0] / EMB;
    int E = in_sizes[1] / EDGE;
    int G = in_sizes[15];                        // data_lens has shape (G,)

    // workspace carve (256B aligned)
    char* w = (char*)d_ws;
    auto alloc = [&](size_t bytes) {
        char* p = w;
        w += (bytes + 255) & ~(size_t)255;
        return p;
    };
    float* hbuf   = (float*)alloc((size_t)N * EMB * 4);  // also featbuf
    float* agg    = (float*)alloc((size_t)N * EMB * 4);
    float* xa     = (float*)alloc((size_t)N * EMB * 4);
    float* xb     = (float*)alloc((size_t)N * EMB * 4);
    float* gate   = (float*)alloc((size_t)N * 4);
    float* gb     = (float*)alloc((size_t)G * EMB * 4);
    float* pooled = (float*)alloc((size_t)G * EMB * 4);
    float* gmax   = (float*)alloc((size_t)G * 4);
    float* denom  = (float*)alloc((size_t)G * 4);
    float* xg_a   = (float*)alloc((size_t)G * EMB * 4);
    float* xg_b   = (float*)alloc((size_t)G * EMB * 4);
    int* deg      = (int*)alloc((size_t)N * 4);
    int* rowptr   = (int*)alloc((size_t)(N + 1) * 4);
    int* cursor   = (int*)alloc((size_t)N * 4);
    int* slot_src = (int*)alloc((size_t)E * 4);
    int* slot_eid = (int*)alloc((size_t)E * 4);
    int* gstart   = (int*)alloc((size_t)(G + 1) * 4);
    int* bsums    = (int*)alloc(1024 * 4);

    const int* esrc = eidx;
    const int* edst = eidx + E;

    int ebl = (E + 255) / 256;
    int NB  = (N + 255) / 256;

    // CSR build (per launch; inputs re-poisoned each call)
    hipMemsetAsync(deg, 0, (size_t)N * 4, stream);
    k_hist<<<ebl, 256, 0, stream>>>(edst, E, deg);
    k_scan1<<<NB, 256, 0, stream>>>(deg, N, rowptr, bsums);
    k_scan2<<<1, 256, 0, stream>>>(bsums, NB);
    k_scan3<<<NB, 256, 0, stream>>>(rowptr, bsums, N, E);
    hipMemcpyAsync(cursor, rowptr, (size_t)N * 4, hipMemcpyDeviceToDevice, stream);
    k_fill<<<ebl, 256, 0, stream>>>(esrc, edst, E, cursor, slot_src, slot_eid);
    k_gstart<<<(G + 256) / 256, 256, 0, stream>>>(batch, N, G, gstart);
    hipMemsetAsync(xg_a, 0, (size_t)G * EMB * 4, stream);

    int gemm_blocks = (N + TM - 1) / TM;
    int gate_blocks = (N + 3) / 4;
    int agg_blocks  = (N + 3) / 4;   // one wave per node

    const float* x_in = x0;
    float* x_chain[STEPS] = {xa, xb, (float*)d_out};
    float* xg_cur = xg_a;
    float* xg_nxt = xg_b;

    for (int s = 0; s < STEPS; ++s) {
        const float* Wm_s = Wm + (size_t)s * 160 * EMB;
        const float* Wa_s = Wa + (size_t)s * 384 * EMB;
        float* x_out = x_chain[s];

        // h = x @ Wm_x + bm
        k_gemm_bias<<<gemm_blocks, 256, 0, stream>>>(x_in, Wm_s, bm + s * EMB, hbuf, N);
        // agg = segment_max(lrelu(h[src] + ea@Wm_e), dst)
        k_agg<<<agg_blocks, 256, 0, stream>>>(hbuf, ea, Wm_s + 128 * EMB, rowptr,
                                              slot_src, slot_eid, agg, N);
        // gb = xg @ Wa_g + ba
        k_gb<<<G, 128, 0, stream>>>(xg_cur, Wa_s + 128 * EMB, ba + s * EMB, gb);
        // x_out = lrelu(x@Wa_x + agg@Wa_a + gb[batch]) + x
        k_gemm_node<<<gemm_blocks, 256, 0, stream>>>(x_in, agg, Wa_s, gb, batch, x_out, N);
        // gate
        k_gate<<<gate_blocks, 256, 0, stream>>>(x_out, Wgate + s * EMB, bgate + s, gate, N);
        k_gseg<<<G, 256, 0, stream>>>(gate, gstart, gmax, denom);
        // featbuf = alpha * lrelu(x_out@Wfeat + bfeat)   (featbuf aliases hbuf)
        k_gemm_feat<<<gemm_blocks, 256, 0, stream>>>(x_out, Wfeat + (size_t)s * EMB * EMB,
                                                     bfeat + s * EMB, gate, gmax, denom,
                                                     batch, hbuf, N);
        k_pool<<<G, 512, 0, stream>>>(hbuf, gstart, pooled);
        // xg update
        k_xg<<<G, 128, 0, stream>>>(pooled, xg_cur, Wt + (size_t)s * 256 * EMB,
                                    bt + s * EMB, xg_nxt);

        x_in = x_out;
        float* tmp = xg_cur; xg_cur = xg_nxt; xg_nxt = tmp;
    }

    // final xg -> tail of d_out
    hipMemcpyAsync((float*)d_out + (size_t)N * EMB, xg_cur, (size_t)G * EMB * 4,
                   hipMemcpyDeviceToDevice, stream);
}

// Round 3
// 1039.009 us; speedup vs baseline: 1.3688x; 1.0295x over previous
//
#include <hip/hip_runtime.h>
#include <hip/hip_bf16.h>

#define EMB 128
#define EDGE 32
#define STEPS 3
#define TM 64

__device__ __forceinline__ float lrelu(float v) { return v > 0.0f ? v : 0.01f * v; }

// ---------------- CSR build ----------------
__global__ void k_hist(const int* __restrict__ dst, int E, int* __restrict__ deg) {
    int e = blockIdx.x * 256 + threadIdx.x;
    if (e < E) atomicAdd(&deg[dst[e]], 1);
}

__global__ void k_scan1(const int* __restrict__ deg, int N, int* __restrict__ rowptr,
                        int* __restrict__ bsums) {
    __shared__ int s[256];
    int t = threadIdx.x;
    int i = blockIdx.x * 256 + t;
    int v = (i < N) ? deg[i] : 0;
    s[t] = v;
    __syncthreads();
#pragma unroll
    for (int off = 1; off < 256; off <<= 1) {
        int x = (t >= off) ? s[t - off] : 0;
        __syncthreads();
        s[t] += x;
        __syncthreads();
    }
    if (i < N) rowptr[i] = s[t] - v;
    if (t == 255) bsums[blockIdx.x] = s[255];
}

__global__ void k_scan2(int* __restrict__ bsums, int NB) {
    __shared__ int s[256];
    __shared__ int carry;
    int t = threadIdx.x;
    if (t == 0) carry = 0;
    __syncthreads();
    for (int base = 0; base < NB; base += 256) {
        int i = base + t;
        int v = (i < NB) ? bsums[i] : 0;
        s[t] = v;
        __syncthreads();
#pragma unroll
        for (int off = 1; off < 256; off <<= 1) {
            int x = (t >= off) ? s[t - off] : 0;
            __syncthreads();
            s[t] += x;
            __syncthreads();
        }
        int excl = s[t] - v + carry;
        if (i < NB) bsums[i] = excl;
        int tot = s[255];
        __syncthreads();
        if (t == 0) carry += tot;
        __syncthreads();
    }
}

__global__ void k_scan3(int* __restrict__ rowptr, const int* __restrict__ bsums, int N, int E) {
    int i = blockIdx.x * 256 + threadIdx.x;
    if (i < N) rowptr[i] += bsums[i >> 8];
    if (i == 0) rowptr[N] = E;
}

__global__ void k_fill(const int* __restrict__ src, const int* __restrict__ dst, int E,
                       int* __restrict__ cursor, int2* __restrict__ slot) {
    int e = blockIdx.x * 256 + threadIdx.x;
    if (e < E) {
        int d = dst[e];
        int p = atomicAdd(&cursor[d], 1);
        slot[p] = make_int2(src[e], e);
    }
}

__global__ void k_gstart(const int* __restrict__ batch, int N, int G, int* __restrict__ gstart) {
    int g = blockIdx.x * blockDim.x + threadIdx.x;
    if (g > G) return;
    int lo = 0, hi = N;
    while (lo < hi) {
        int mid = (lo + hi) >> 1;
        if (batch[mid] < g) lo = mid + 1; else hi = mid;
    }
    gstart[g] = lo;
}

// ---------------- GEMM core: 64-row tile, 128 cols, K=128 ----------------
__device__ __forceinline__ void gemm_stage_A(const float* __restrict__ A, int row0, int N,
                                             float* As) {
    int tid = threadIdx.x;
#pragma unroll
    for (int i = 0; i < 8; ++i) {
        int idx = tid + i * 256;       // float4 index into 64x128 tile
        int r = idx >> 5;              // 32 float4 per row
        int c4 = idx & 31;
        float4 v = make_float4(0.f, 0.f, 0.f, 0.f);
        if (row0 + r < N) v = ((const float4*)(A + (size_t)(row0 + r) * EMB))[c4];
        ((float4*)As)[idx] = v;
    }
}

__device__ __forceinline__ void gemm_mainloop(const float* __restrict__ W, const float* As,
                                              float* Ws, float4 acc[8]) {
    int tid = threadIdx.x;
    int tx = tid & 31, ty = tid >> 5;
    for (int kc = 0; kc < 2; ++kc) {
        __syncthreads();
#pragma unroll
        for (int i = 0; i < 8; ++i) {
            int idx = tid + i * 256;
            ((float4*)Ws)[idx] = ((const float4*)(W + (size_t)(kc * 64) * EMB))[idx];
        }
        __syncthreads();
#pragma unroll 4
        for (int k0 = 0; k0 < 64; k0 += 4) {
            float4 w0 = ((const float4*)Ws)[(k0 + 0) * 32 + tx];
            float4 w1 = ((const float4*)Ws)[(k0 + 1) * 32 + tx];
            float4 w2 = ((const float4*)Ws)[(k0 + 2) * 32 + tx];
            float4 w3 = ((const float4*)Ws)[(k0 + 3) * 32 + tx];
            int kidx = (kc * 64 + k0) >> 2;
#pragma unroll
            for (int i = 0; i < 8; ++i) {
                float4 a = ((const float4*)As)[(ty * 8 + i) * 32 + kidx];
                acc[i].x = fmaf(a.x, w0.x, fmaf(a.y, w1.x, fmaf(a.z, w2.x, fmaf(a.w, w3.x, acc[i].x))));
                acc[i].y = fmaf(a.x, w0.y, fmaf(a.y, w1.y, fmaf(a.z, w2.y, fmaf(a.w, w3.y, acc[i].y))));
                acc[i].z = fmaf(a.x, w0.z, fmaf(a.y, w1.z, fmaf(a.z, w2.z, fmaf(a.w, w3.z, acc[i].z))));
                acc[i].w = fmaf(a.x, w0.w, fmaf(a.y, w1.w, fmaf(a.z, w2.w, fmaf(a.w, w3.w, acc[i].w))));
            }
        }
    }
}

// h = x @ Wm_x + bm
__global__ __launch_bounds__(256, 2) void k_gemm_bias(const float* __restrict__ A,
                                                      const float* __restrict__ W,
                                                      const float* __restrict__ bias,
                                                      float* __restrict__ C, int N) {
    __shared__ float As[TM * EMB];
    __shared__ float Ws[64 * EMB];
    float4 acc[8] = {};
    int row0 = blockIdx.x * TM;
    gemm_stage_A(A, row0, N, As);
    gemm_mainloop(W, As, Ws, acc);
    int tx = threadIdx.x & 31, ty = threadIdx.x >> 5;
    float4 b = ((const float4*)bias)[tx];
#pragma unroll
    for (int i = 0; i < 8; ++i) {
        int r = row0 + ty * 8 + i;
        if (r < N) {
            float4 o;
            o.x = acc[i].x + b.x; o.y = acc[i].y + b.y;
            o.z = acc[i].z + b.z; o.w = acc[i].w + b.w;
            ((float4*)(C + (size_t)r * EMB))[tx] = o;
        }
    }
}

// x_out = lrelu(x@Wa_x + agg@Wa_a + gb[batch]) + x
__global__ __launch_bounds__(256, 2) void k_gemm_node(const float* __restrict__ x,
                                                      const float* __restrict__ agg,
                                                      const float* __restrict__ Wa,
                                                      const float* __restrict__ gb,
                                                      const int* __restrict__ batch,
                                                      float* __restrict__ C, int N) {
    __shared__ float As[TM * EMB];
    __shared__ float Ws[64 * EMB];
    float4 acc[8] = {};
    int row0 = blockIdx.x * TM;
    gemm_stage_A(x, row0, N, As);
    gemm_mainloop(Wa, As, Ws, acc);            // rows 0..127 (x part)
    __syncthreads();
    gemm_stage_A(agg, row0, N, As);
    gemm_mainloop(Wa + 256 * EMB, As, Ws, acc); // rows 256..383 (agg part)
    int tx = threadIdx.x & 31, ty = threadIdx.x >> 5;
#pragma unroll
    for (int i = 0; i < 8; ++i) {
        int r = row0 + ty * 8 + i;
        if (r < N) {
            int g = batch[r];
            float4 b = ((const float4*)(gb + (size_t)g * EMB))[tx];
            float4 res = ((const float4*)(x + (size_t)r * EMB))[tx];
            float4 o;
            o.x = lrelu(acc[i].x + b.x) + res.x;
            o.y = lrelu(acc[i].y + b.y) + res.y;
            o.z = lrelu(acc[i].z + b.z) + res.z;
            o.w = lrelu(acc[i].w + b.w) + res.w;
            ((float4*)(C + (size_t)r * EMB))[tx] = o;
        }
    }
}

// featbuf = alpha * lrelu(x@Wfeat + bfeat)
__global__ __launch_bounds__(256, 2) void k_gemm_feat(const float* __restrict__ A,
                                                      const float* __restrict__ W,
                                                      const float* __restrict__ bias,
                                                      const float* __restrict__ gate,
                                                      const float* __restrict__ gmax,
                                                      const float* __restrict__ denom,
                                                      const int* __restrict__ batch,
                                                      float* __restrict__ C, int N) {
    __shared__ float As[TM * EMB];
    __shared__ float Ws[64 * EMB];
    float4 acc[8] = {};
    int row0 = blockIdx.x * TM;
    gemm_stage_A(A, row0, N, As);
    gemm_mainloop(W, As, Ws, acc);
    int tx = threadIdx.x & 31, ty = threadIdx.x >> 5;
    float4 b = ((const float4*)bias)[tx];
#pragma unroll
    for (int i = 0; i < 8; ++i) {
        int r = row0 + ty * 8 + i;
        if (r < N) {
            int g = batch[r];
            float alpha = __expf(gate[r] - gmax[g]) / denom[g];
            float4 o;
            o.x = alpha * lrelu(acc[i].x + b.x);
            o.y = alpha * lrelu(acc[i].y + b.y);
            o.z = alpha * lrelu(acc[i].z + b.z);
            o.w = alpha * lrelu(acc[i].w + b.w);
            ((float4*)(C + (size_t)r * EMB))[tx] = o;
        }
    }
}

// ---------------- fused edge message + segment-max ----------------
// One wave per node. Wm_e fragment (64 floats/lane) PINNED into VGPRs via
// empty asm (R2 showed VGPR_Count=48 -> compiler rematerialized the loads
// inside the FMA loop -> VMEM-issue-bound). ea rows loaded as explicit
// float4x8; slot array is int2 (src,eid) -> one 8B load per edge.
__global__ __launch_bounds__(256) void k_agg(const float* __restrict__ h,
                                             const float* __restrict__ ea,
                                             const float* __restrict__ Wme,
                                             const int* __restrict__ rowptr,
                                             const int2* __restrict__ slot,
                                             float* __restrict__ agg, int N) {
    int n = blockIdx.x * 4 + (threadIdx.x >> 6);
    if (n >= N) return;
    int lane = threadIdx.x & 63;

    // load + pin the Wm_e fragment (2 output channels per lane)
    float2 w2[32];
#pragma unroll
    for (int k = 0; k < 32; ++k) w2[k] = *(const float2*)(Wme + k * EMB + lane * 2);
#pragma unroll
    for (int k = 0; k < 32; ++k)
        asm volatile("" : "+v"(w2[k].x), "+v"(w2[k].y));

    int r0 = rowptr[n], r1 = rowptr[n + 1];
    float2 outv;
    if (r0 == r1) {
        outv = make_float2(0.f, 0.f);
    } else {
        float2 vmax0 = make_float2(-__builtin_inff(), -__builtin_inff());
        float2 vmax1 = make_float2(-__builtin_inff(), -__builtin_inff());
        int p = r0;
        for (; p + 1 < r1; p += 2) {
            int2 s0 = slot[p];
            int2 s1 = slot[p + 1];
            int src0 = __builtin_amdgcn_readfirstlane(s0.x);
            int eid0 = __builtin_amdgcn_readfirstlane(s0.y);
            int src1 = __builtin_amdgcn_readfirstlane(s1.x);
            int eid1 = __builtin_amdgcn_readfirstlane(s1.y);
            const float4* ea0 = (const float4*)(ea + (size_t)eid0 * EDGE);
            const float4* ea1 = (const float4*)(ea + (size_t)eid1 * EDGE);
            float2 a0 = *(const float2*)(h + (size_t)src0 * EMB + lane * 2);
            float2 a1 = *(const float2*)(h + (size_t)src1 * EMB + lane * 2);
            float4 e0[8], e1[8];
#pragma unroll
            for (int q = 0; q < 8; ++q) { e0[q] = ea0[q]; e1[q] = ea1[q]; }
#pragma unroll
            for (int q = 0; q < 8; ++q) {
                const float* f0 = (const float*)&e0[q];
                const float* f1 = (const float*)&e1[q];
#pragma unroll
                for (int j = 0; j < 4; ++j) {
                    int k = q * 4 + j;
                    a0.x = fmaf(f0[j], w2[k].x, a0.x);
                    a0.y = fmaf(f0[j], w2[k].y, a0.y);
                    a1.x = fmaf(f1[j], w2[k].x, a1.x);
                    a1.y = fmaf(f1[j], w2[k].y, a1.y);
                }
            }
            vmax0.x = fmaxf(vmax0.x, lrelu(a0.x));
            vmax0.y = fmaxf(vmax0.y, lrelu(a0.y));
            vmax1.x = fmaxf(vmax1.x, lrelu(a1.x));
            vmax1.y = fmaxf(vmax1.y, lrelu(a1.y));
        }
        if (p < r1) {
            int2 s0 = slot[p];
            int src0 = __builtin_amdgcn_readfirstlane(s0.x);
            int eid0 = __builtin_amdgcn_readfirstlane(s0.y);
            const float4* ea0 = (const float4*)(ea + (size_t)eid0 * EDGE);
            float2 a0 = *(const float2*)(h + (size_t)src0 * EMB + lane * 2);
            float4 e0[8];
#pragma unroll
            for (int q = 0; q < 8; ++q) e0[q] = ea0[q];
#pragma unroll
            for (int q = 0; q < 8; ++q) {
                const float* f0 = (const float*)&e0[q];
#pragma unroll
                for (int j = 0; j < 4; ++j) {
                    int k = q * 4 + j;
                    a0.x = fmaf(f0[j], w2[k].x, a0.x);
                    a0.y = fmaf(f0[j], w2[k].y, a0.y);
                }
            }
            vmax0.x = fmaxf(vmax0.x, lrelu(a0.x));
            vmax0.y = fmaxf(vmax0.y, lrelu(a0.y));
        }
        outv.x = fmaxf(vmax0.x, vmax1.x);
        outv.y = fmaxf(vmax0.y, vmax1.y);
    }
    *(float2*)(agg + (size_t)n * EMB + lane * 2) = outv;
}

// ---------------- small per-graph kernels ----------------
// gb = xg @ Wa_g + ba   (G rows)
__global__ __launch_bounds__(128) void k_gb(const float* __restrict__ xg,
                                            const float* __restrict__ WaG,
                                            const float* __restrict__ ba,
                                            float* __restrict__ gb) {
    int g = blockIdx.x, c = threadIdx.x;
    __shared__ float row[EMB];
    row[c] = xg[(size_t)g * EMB + c];
    __syncthreads();
    float acc = ba[c];
#pragma unroll 8
    for (int k = 0; k < EMB; ++k) acc = fmaf(row[k], WaG[(size_t)k * EMB + c], acc);
    gb[(size_t)g * EMB + c] = acc;
}

// gate[n] = x[n] . wg + bg
__global__ __launch_bounds__(256) void k_gate(const float* __restrict__ x,
                                              const float* __restrict__ wg,
                                              const float* __restrict__ bg,
                                              float* __restrict__ gate, int N) {
    int n = blockIdx.x * 4 + (threadIdx.x >> 6);
    int lane = threadIdx.x & 63;
    if (n >= N) return;
    const float* xr = x + (size_t)n * EMB;
    float v = fmaf(xr[lane], wg[lane], xr[lane + 64] * wg[lane + 64]);
#pragma unroll
    for (int off = 32; off; off >>= 1) v += __shfl_xor(v, off, 64);
    if (lane == 0) gate[n] = v + bg[0];
}

// per-graph max + sum(exp)
__global__ __launch_bounds__(256) void k_gseg(const float* __restrict__ gate,
                                              const int* __restrict__ gstart,
                                              float* __restrict__ gmax,
                                              float* __restrict__ denom) {
    int g = blockIdx.x;
    int s0 = gstart[g], s1 = gstart[g + 1];
    __shared__ float red[256];
    int t = threadIdx.x;
    float mx = -__builtin_inff();
    for (int i = s0 + t; i < s1; i += 256) mx = fmaxf(mx, gate[i]);
    red[t] = mx;
    __syncthreads();
#pragma unroll
    for (int off = 128; off; off >>= 1) {
        if (t < off) red[t] = fmaxf(red[t], red[t + off]);
        __syncthreads();
    }
    float m = red[0];
    __syncthreads();
    float sum = 0.f;
    for (int i = s0 + t; i < s1; i += 256) sum += __expf(gate[i] - m);
    red[t] = sum;
    __syncthreads();
#pragma unroll
    for (int off = 128; off; off >>= 1) {
        if (t < off) red[t] += red[t + off];
        __syncthreads();
    }
    if (t == 0) {
        gmax[g] = (s1 > s0) ? m : 0.f;
        denom[g] = red[0];
    }
}

// pooled[g] = sum of featbuf rows in [gstart[g], gstart[g+1]) — 4 rows/iter
__global__ __launch_bounds__(512) void k_pool(const float* __restrict__ feat,
                                              const int* __restrict__ gstart,
                                              float* __restrict__ pooled) {
    int g = blockIdx.x;
    int c = threadIdx.x & 127;
    int r = threadIdx.x >> 7;   // 0..3
    int s0 = gstart[g], s1 = gstart[g + 1];
    float s = 0.f;
    for (int i = s0 + r; i < s1; i += 4) s += feat[(size_t)i * EMB + c];
    __shared__ float red[512];
    red[threadIdx.x] = s;
    __syncthreads();
    if (threadIdx.x < 256) red[threadIdx.x] += red[threadIdx.x + 256];
    __syncthreads();
    if (threadIdx.x < 128)
        pooled[(size_t)g * EMB + threadIdx.x] = red[threadIdx.x] + red[threadIdx.x + 128];
}

// xg_out = lrelu([pooled, xg] @ Wt + bt) + xg
__global__ __launch_bounds__(128) void k_xg(const float* __restrict__ pooled,
                                            const float* __restrict__ xg,
                                            const float* __restrict__ Wt,
                                            const float* __restrict__ bt,
                                            float* __restrict__ xg_out) {
    int g = blockIdx.x, c = threadIdx.x;
    __shared__ float row[256];
    row[c] = pooled[(size_t)g * EMB + c];
    row[c + 128] = xg[(size_t)g * EMB + c];
    __syncthreads();
    float acc = bt[c];
#pragma unroll 8
    for (int k = 0; k < 256; ++k) acc = fmaf(row[k], Wt[(size_t)k * EMB + c], acc);
    xg_out[(size_t)g * EMB + c] = lrelu(acc) + row[c + 128];
}

// ---------------- launch ----------------
extern "C" void kernel_launch(void* const* d_in, const int* in_sizes, int n_in,
                              void* d_out, int out_size, void* d_ws, size_t ws_size,
                              hipStream_t stream) {
    const float* x0    = (const float*)d_in[0];
    const float* ea    = (const float*)d_in[1];
    const float* Wm    = (const float*)d_in[2];
    const float* bm    = (const float*)d_in[3];
    const float* Wa    = (const float*)d_in[4];
    const float* ba    = (const float*)d_in[5];
    const float* Wgate = (const float*)d_in[6];
    const float* bgate = (const float*)d_in[7];
    const float* Wfeat = (const float*)d_in[8];
    const float* bfeat = (const float*)d_in[9];
    const float* Wt    = (const float*)d_in[10];
    const float* bt    = (const float*)d_in[11];
    const int*   eidx  = (const int*)d_in[12];   // [2,E]: src then dst
    const int*   batch = (const int*)d_in[13];

    int N = in_sizes[0] / EMB;
    int E = in_sizes[1] / EDGE;
    int G = in_sizes[15];                        // data_lens has shape (G,)

    // workspace carve (256B aligned)
    char* w = (char*)d_ws;
    auto alloc = [&](size_t bytes) {
        char* p = w;
        w += (bytes + 255) & ~(size_t)255;
        return p;
    };
    float* hbuf   = (float*)alloc((size_t)N * EMB * 4);  // also featbuf
    float* agg    = (float*)alloc((size_t)N * EMB * 4);
    float* xa     = (float*)alloc((size_t)N * EMB * 4);
    float* xb     = (float*)alloc((size_t)N * EMB * 4);
    float* gate   = (float*)alloc((size_t)N * 4);
    float* gb     = (float*)alloc((size_t)G * EMB * 4);
    float* pooled = (float*)alloc((size_t)G * EMB * 4);
    float* gmax   = (float*)alloc((size_t)G * 4);
    float* denom  = (float*)alloc((size_t)G * 4);
    float* xg_a   = (float*)alloc((size_t)G * EMB * 4);
    float* xg_b   = (float*)alloc((size_t)G * EMB * 4);
    int* deg      = (int*)alloc((size_t)N * 4);
    int* rowptr   = (int*)alloc((size_t)(N + 1) * 4);
    int* cursor   = (int*)alloc((size_t)N * 4);
    int2* slot    = (int2*)alloc((size_t)E * 8);
    int* gstart   = (int*)alloc((size_t)(G + 1) * 4);
    int* bsums    = (int*)alloc(1024 * 4);

    const int* esrc = eidx;
    const int* edst = eidx + E;

    int ebl = (E + 255) / 256;
    int NB  = (N + 255) / 256;

    // CSR build (per launch; inputs re-poisoned each call)
    hipMemsetAsync(deg, 0, (size_t)N * 4, stream);
    k_hist<<<ebl, 256, 0, stream>>>(edst, E, deg);
    k_scan1<<<NB, 256, 0, stream>>>(deg, N, rowptr, bsums);
    k_scan2<<<1, 256, 0, stream>>>(bsums, NB);
    k_scan3<<<NB, 256, 0, stream>>>(rowptr, bsums, N, E);
    hipMemcpyAsync(cursor, rowptr, (size_t)N * 4, hipMemcpyDeviceToDevice, stream);
    k_fill<<<ebl, 256, 0, stream>>>(esrc, edst, E, cursor, slot);
    k_gstart<<<(G + 256) / 256, 256, 0, stream>>>(batch, N, G, gstart);
    hipMemsetAsync(xg_a, 0, (size_t)G * EMB * 4, stream);

    int gemm_blocks = (N + TM - 1) / TM;
    int gate_blocks = (N + 3) / 4;
    int agg_blocks  = (N + 3) / 4;   // one wave per node

    const float* x_in = x0;
    float* x_chain[STEPS] = {xa, xb, (float*)d_out};
    float* xg_cur = xg_a;
    float* xg_nxt = xg_b;

    for (int s = 0; s < STEPS; ++s) {
        const float* Wm_s = Wm + (size_t)s * 160 * EMB;
        const float* Wa_s = Wa + (size_t)s * 384 * EMB;
        float* x_out = x_chain[s];

        // h = x @ Wm_x + bm
        k_gemm_bias<<<gemm_blocks, 256, 0, stream>>>(x_in, Wm_s, bm + s * EMB, hbuf, N);
        // agg = segment_max(lrelu(h[src] + ea@Wm_e), dst)
        k_agg<<<agg_blocks, 256, 0, stream>>>(hbuf, ea, Wm_s + 128 * EMB, rowptr,
                                              slot, agg, N);
        // gb = xg @ Wa_g + ba
        k_gb<<<G, 128, 0, stream>>>(xg_cur, Wa_s + 128 * EMB, ba + s * EMB, gb);
        // x_out = lrelu(x@Wa_x + agg@Wa_a + gb[batch]) + x
        k_gemm_node<<<gemm_blocks, 256, 0, stream>>>(x_in, agg, Wa_s, gb, batch, x_out, N);
        // gate
        k_gate<<<gate_blocks, 256, 0, stream>>>(x_out, Wgate + s * EMB, bgate + s, gate, N);
        k_gseg<<<G, 256, 0, stream>>>(gate, gstart, gmax, denom);
        // featbuf = alpha * lrelu(x_out@Wfeat + bfeat)   (featbuf aliases hbuf)
        k_gemm_feat<<<gemm_blocks, 256, 0, stream>>>(x_out, Wfeat + (size_t)s * EMB * EMB,
                                                     bfeat + s * EMB, gate, gmax, denom,
                                                     batch, hbuf, N);
        k_pool<<<G, 512, 0, stream>>>(hbuf, gstart, pooled);
        // xg update
        k_xg<<<G, 128, 0, stream>>>(pooled, xg_cur, Wt + (size_t)s * 256 * EMB,
                                    bt + s * EMB, xg_nxt);

        x_in = x_out;
        float* tmp = xg_cur; xg_cur = xg_nxt; xg_nxt = tmp;
    }

    // final xg -> tail of d_out
    hipMemcpyAsync((float*)d_out + (size_t)N * EMB, xg_cur, (size_t)G * EMB * 4,
                   hipMemcpyDeviceToDevice, stream);
}

// Round 4
// 860.506 us; speedup vs baseline: 1.6527x; 1.2074x over previous
//
#include <hip/hip_runtime.h>

#define EMB 128
#define EDGE 32
#define STEPS 3

typedef short bf8s __attribute__((ext_vector_type(8)));
typedef float f32x4 __attribute__((ext_vector_type(4)));
typedef unsigned short u16x4 __attribute__((ext_vector_type(4)));

__device__ __forceinline__ float lrelu(float v) { return v > 0.0f ? v : 0.01f * v; }
// fp32 -> bf16 round-to-nearest-even (inputs are finite; no NaN handling needed)
__device__ __forceinline__ unsigned short f2bf(float f) {
    unsigned u = __float_as_uint(f);
    u += 0x7fffu + ((u >> 16) & 1u);
    return (unsigned short)(u >> 16);
}
__device__ __forceinline__ float bf2f(unsigned short s) {
    return __uint_as_float(((unsigned)s) << 16);
}

// ---------------- CSR build ----------------
__global__ void k_hist(const int* __restrict__ dst, int E, int* __restrict__ deg) {
    int e = blockIdx.x * 256 + threadIdx.x;
    if (e < E) atomicAdd(&deg[dst[e]], 1);
}

__global__ void k_scan1(const int* __restrict__ deg, int N, int* __restrict__ rowptr,
                        int* __restrict__ bsums) {
    __shared__ int s[256];
    int t = threadIdx.x;
    int i = blockIdx.x * 256 + t;
    int v = (i < N) ? deg[i] : 0;
    s[t] = v;
    __syncthreads();
#pragma unroll
    for (int off = 1; off < 256; off <<= 1) {
        int x = (t >= off) ? s[t - off] : 0;
        __syncthreads();
        s[t] += x;
        __syncthreads();
    }
    if (i < N) rowptr[i] = s[t] - v;
    if (t == 255) bsums[blockIdx.x] = s[255];
}

__global__ void k_scan2(int* __restrict__ bsums, int NB) {
    __shared__ int s[256];
    __shared__ int carry;
    int t = threadIdx.x;
    if (t == 0) carry = 0;
    __syncthreads();
    for (int base = 0; base < NB; base += 256) {
        int i = base + t;
        int v = (i < NB) ? bsums[i] : 0;
        s[t] = v;
        __syncthreads();
#pragma unroll
        for (int off = 1; off < 256; off <<= 1) {
            int x = (t >= off) ? s[t - off] : 0;
            __syncthreads();
            s[t] += x;
            __syncthreads();
        }
        int excl = s[t] - v + carry;
        if (i < NB) bsums[i] = excl;
        int tot = s[255];
        __syncthreads();
        if (t == 0) carry += tot;
        __syncthreads();
    }
}

__global__ void k_scan3(int* __restrict__ rowptr, const int* __restrict__ bsums, int N, int E) {
    int i = blockIdx.x * 256 + threadIdx.x;
    if (i < N) rowptr[i] += bsums[i >> 8];
    if (i == 0) rowptr[N] = E;
}

__global__ void k_fill(const int* __restrict__ src, const int* __restrict__ dst, int E,
                       int* __restrict__ cursor, int2* __restrict__ slot) {
    int e = blockIdx.x * 256 + threadIdx.x;
    if (e < E) {
        int d = dst[e];
        int p = atomicAdd(&cursor[d], 1);
        slot[p] = make_int2(src[e], e);
    }
}

__global__ void k_gstart(const int* __restrict__ batch, int N, int G, int* __restrict__ gstart) {
    int g = blockIdx.x * blockDim.x + threadIdx.x;
    if (g > G) return;
    int lo = 0, hi = N;
    while (lo < hi) {
        int mid = (lo + hi) >> 1;
        if (batch[mid] < g) lo = mid + 1; else hi = mid;
    }
    gstart[g] = lo;
}

// ---------------- weight prepack: fp32 row-major -> bf16 B-fragment order ----------------
// B-frag for mfma_f32_16x16x32_bf16: lane holds col n=lane&15, k = (lane>>4)*8 + j.
// Linear layout per 128x128 unit: [kc(4)][ctile(8)][lane(64)][j(8)], 16384 ushort.
// 15 units: per step s: 0=Wm_x(128 rows) 1=Wm_e(32 rows) 2=Wa_x 3=Wa_agg 4=Wfeat.
__global__ __launch_bounds__(256) void k_wpack(const float* __restrict__ Wm,
                                               const float* __restrict__ Wa,
                                               const float* __restrict__ Wfeat,
                                               unsigned short* __restrict__ wpack) {
    int gid = blockIdx.x * 256 + threadIdx.x;
    int unit = gid >> 14;
    int e = gid & 16383;
    int s = unit / 5, u = unit % 5;
    const float* src; int rows;
    switch (u) {
        case 0: src = Wm + (size_t)s * 160 * EMB;             rows = 128; break;
        case 1: src = Wm + (size_t)s * 160 * EMB + 128 * EMB; rows = 32;  break;
        case 2: src = Wa + (size_t)s * 384 * EMB;             rows = 128; break;
        case 3: src = Wa + (size_t)s * 384 * EMB + 256 * EMB; rows = 128; break;
        default: src = Wfeat + (size_t)s * EMB * EMB;         rows = 128; break;
    }
    int k = e >> 7, n = e & 127;
    if (k >= rows) return;
    unsigned short b = f2bf(src[(size_t)k * EMB + n]);
    int kc = k >> 5, c = n >> 4, lane = (n & 15) | (((k & 31) >> 3) << 4), j = k & 7;
    wpack[(size_t)unit * 16384 + ((size_t)(kc * 8 + c) * 64 + lane) * 8 + j] = b;
}

// ---------------- MFMA GEMM core: 64 rows x 128 cols, K=128 ----------------
// A-frag: lane holds row m=lane&15 (of a 16-row tile), k=(lane>>4)*8+j.
// lA layout: [kc(4)][rowtile(4)][lane(64)][j(8)] ushort = 16 KB.
__device__ __forceinline__ void stageA(const float* __restrict__ A, int row0, int N,
                                       unsigned short* lA, int tid) {
#pragma unroll
    for (int i = 0; i < 8; ++i) {
        int idx = tid + i * 256;          // 2048 float4 of the 64x128 tile
        int m = idx >> 5, c4 = idx & 31, k0 = c4 * 4;
        float4 v = make_float4(0.f, 0.f, 0.f, 0.f);
        if (row0 + m < N) v = ((const float4*)(A + (size_t)(row0 + m) * EMB))[c4];
        int kc = k0 >> 5, oct = (k0 & 31) >> 3, j0 = k0 & 7;
        int lane = (m & 15) | (oct << 4), rt = m >> 4;
        u16x4 pk = { f2bf(v.x), f2bf(v.y), f2bf(v.z), f2bf(v.w) };
        *(u16x4*)&lA[(((kc * 4 + rt) * 64 + lane) * 8) + j0] = pk;
    }
}
__device__ __forceinline__ void stageB(const unsigned short* __restrict__ Bp,
                                       unsigned short* lB, int tid) {
#pragma unroll
    for (int i = 0; i < 8; ++i) {
        int idx = tid + i * 256;          // 2048 x 16B = 32 KB
        ((int4*)lB)[idx] = ((const int4*)Bp)[idx];
    }
}
__device__ __forceinline__ void mfma128(const unsigned short* lA, const unsigned short* lB,
                                        f32x4 acc[8], int wv, int lane) {
#pragma unroll
    for (int kc = 0; kc < 4; ++kc) {
        bf8s a = *(const bf8s*)&lA[((kc * 4 + wv) * 64 + lane) * 8];
#pragma unroll
        for (int c = 0; c < 8; ++c) {
            bf8s b = *(const bf8s*)&lB[((kc * 8 + c) * 64 + lane) * 8];
            acc[c] = __builtin_amdgcn_mfma_f32_16x16x32_bf16(a, b, acc[c], 0, 0, 0);
        }
    }
}

// h = x @ Wm_x + bm
__global__ __launch_bounds__(256) void k_gemm_bias(const float* __restrict__ A,
                                                   const unsigned short* __restrict__ Bp,
                                                   const float* __restrict__ bias,
                                                   float* __restrict__ C, int N) {
    __shared__ unsigned short lA[8192];
    __shared__ unsigned short lB[16384];
    int tid = threadIdx.x, wv = tid >> 6, lane = tid & 63;
    int row0 = blockIdx.x * 64;
    stageA(A, row0, N, lA, tid);
    stageB(Bp, lB, tid);
    __syncthreads();
    f32x4 acc[8];
#pragma unroll
    for (int c = 0; c < 8; ++c) acc[c] = (f32x4){0.f, 0.f, 0.f, 0.f};
    mfma128(lA, lB, acc, wv, lane);
    int li = lane & 15, quad = lane >> 4;
#pragma unroll
    for (int c = 0; c < 8; ++c) {
        int col = c * 16 + li;
        float b = bias[col];
#pragma unroll
        for (int rr = 0; rr < 4; ++rr) {
            int m = row0 + wv * 16 + quad * 4 + rr;
            if (m < N) C[(size_t)m * EMB + col] = acc[c][rr] + b;
        }
    }
}

// x_out = lrelu(x@Wa_x + agg@Wa_agg + gb[batch]) + x   (x_out may alias x: each
// block reads/writes only its own 64 rows; epilogue reads residual before store)
__global__ __launch_bounds__(256) void k_gemm_node(const float* __restrict__ x,
                                                   const float* __restrict__ agg,
                                                   const unsigned short* __restrict__ BpX,
                                                   const unsigned short* __restrict__ BpA,
                                                   const float* __restrict__ gb,
                                                   const int* __restrict__ batch,
                                                   float* __restrict__ xout, int N) {
    __shared__ unsigned short lA[8192];
    __shared__ unsigned short lB[16384];
    int tid = threadIdx.x, wv = tid >> 6, lane = tid & 63;
    int row0 = blockIdx.x * 64;
    stageA(x, row0, N, lA, tid);
    stageB(BpX, lB, tid);
    __syncthreads();
    f32x4 acc[8];
#pragma unroll
    for (int c = 0; c < 8; ++c) acc[c] = (f32x4){0.f, 0.f, 0.f, 0.f};
    mfma128(lA, lB, acc, wv, lane);
    __syncthreads();
    stageA(agg, row0, N, lA, tid);
    stageB(BpA, lB, tid);
    __syncthreads();
    mfma128(lA, lB, acc, wv, lane);
    int li = lane & 15, quad = lane >> 4;
#pragma unroll
    for (int c = 0; c < 8; ++c) {
        int col = c * 16 + li;
#pragma unroll
        for (int rr = 0; rr < 4; ++rr) {
            int m = row0 + wv * 16 + quad * 4 + rr;
            if (m < N) {
                int g = batch[m];
                float b = gb[(size_t)g * EMB + col];
                float res = x[(size_t)m * EMB + col];
                xout[(size_t)m * EMB + col] = lrelu(acc[c][rr] + b) + res;
            }
        }
    }
}

// featbuf = alpha * lrelu(x@Wfeat + bfeat)
__global__ __launch_bounds__(256) void k_gemm_feat(const float* __restrict__ A,
                                                   const unsigned short* __restrict__ Bp,
                                                   const float* __restrict__ bias,
                                                   const float* __restrict__ gate,
                                                   const float* __restrict__ gmax,
                                                   const float* __restrict__ denom,
                                                   const int* __restrict__ batch,
                                                   float* __restrict__ C, int N) {
    __shared__ unsigned short lA[8192];
    __shared__ unsigned short lB[16384];
    int tid = threadIdx.x, wv = tid >> 6, lane = tid & 63;
    int row0 = blockIdx.x * 64;
    stageA(A, row0, N, lA, tid);
    stageB(Bp, lB, tid);
    __syncthreads();
    f32x4 acc[8];
#pragma unroll
    for (int c = 0; c < 8; ++c) acc[c] = (f32x4){0.f, 0.f, 0.f, 0.f};
    mfma128(lA, lB, acc, wv, lane);
    int li = lane & 15, quad = lane >> 4;
    float alpha[4];
#pragma unroll
    for (int rr = 0; rr < 4; ++rr) {
        int m = row0 + wv * 16 + quad * 4 + rr;
        if (m < N) {
            int g = batch[m];
            alpha[rr] = __expf(gate[m] - gmax[g]) / denom[g];
        } else alpha[rr] = 0.f;
    }
#pragma unroll
    for (int c = 0; c < 8; ++c) {
        int col = c * 16 + li;
        float b = bias[col];
#pragma unroll
        for (int rr = 0; rr < 4; ++rr) {
            int m = row0 + wv * 16 + quad * 4 + rr;
            if (m < N) C[(size_t)m * EMB + col] = alpha[rr] * lrelu(acc[c][rr] + b);
        }
    }
}

// ---------------- edge messages: emsg = ea[eid] @ Wm_e (bf16 out, MFMA) ----------------
// One wave per 16-edge tile (dst-sorted order). A-frag gathered directly into
// registers; B (Wm_e, K=32 -> single kc) staged in LDS.
__global__ __launch_bounds__(256) void k_emsg(const float* __restrict__ ea,
                                              const int2* __restrict__ slot,
                                              const unsigned short* __restrict__ Bp,
                                              unsigned short* __restrict__ emsg,
                                              int E, int ntiles, int c0, int nct) {
    __shared__ unsigned short lB[4096];
    int tid = threadIdx.x;
    ((int4*)lB)[tid]       = ((const int4*)Bp)[tid];
    ((int4*)lB)[tid + 256] = ((const int4*)Bp)[tid + 256];
    __syncthreads();
    int wv = tid >> 6, lane = tid & 63;
    int t = blockIdx.x * 4 + wv;
    if (t >= ntiles) return;
    int r = lane & 15, oct = lane >> 4;
    int p = t * 16 + r;
    if (p >= E) p = E - 1;
    int eid = slot[p].y;
    const float4* ear = (const float4*)(ea + (size_t)eid * EDGE);
    float4 v0 = ear[oct * 2], v1 = ear[oct * 2 + 1];
    bf8s a;
    a[0] = (short)f2bf(v0.x); a[1] = (short)f2bf(v0.y);
    a[2] = (short)f2bf(v0.z); a[3] = (short)f2bf(v0.w);
    a[4] = (short)f2bf(v1.x); a[5] = (short)f2bf(v1.y);
    a[6] = (short)f2bf(v1.z); a[7] = (short)f2bf(v1.w);
    int nc = nct * 16;
    for (int ci = 0; ci < nct; ++ci) {
        int c = c0 + ci;
        bf8s b = *(const bf8s*)&lB[(c * 64 + lane) * 8];
        f32x4 acc = (f32x4){0.f, 0.f, 0.f, 0.f};
        acc = __builtin_amdgcn_mfma_f32_16x16x32_bf16(a, b, acc, 0, 0, 0);
        int col = ci * 16 + r;   // C layout: col = lane&15
#pragma unroll
        for (int rr = 0; rr < 4; ++rr) {
            int po = t * 16 + oct * 4 + rr;   // C row = quad*4 + reg
            if (po < E) emsg[(size_t)po * nc + col] = f2bf(acc[rr]);
        }
    }
}

// ---------------- segment-max: agg[n][c] = max_p lrelu(h[src_p][c] + emsg[p][c]) ----------------
__global__ __launch_bounds__(256) void k_aggl(const float* __restrict__ h,
                                              const unsigned short* __restrict__ emsg,
                                              const int2* __restrict__ slot,
                                              const int* __restrict__ rowptr,
                                              float* __restrict__ agg,
                                              int N, int c0, int nc) {
    int wv = threadIdx.x >> 6, lane = threadIdx.x & 63;
    int n = blockIdx.x * 4 + wv;
    if (n >= N) return;
    int r0 = rowptr[n], r1 = rowptr[n + 1];
    if (nc == 128) {
        float2 vm = make_float2(-__builtin_inff(), -__builtin_inff());
        for (int p = r0; p < r1; ++p) {
            int src = __builtin_amdgcn_readfirstlane(slot[p].x);
            float2 hb = *(const float2*)(h + (size_t)src * EMB + lane * 2);
            unsigned me = *(const unsigned*)(emsg + (size_t)p * 128 + lane * 2);
            vm.x = fmaxf(vm.x, lrelu(hb.x + bf2f((unsigned short)me)));
            vm.y = fmaxf(vm.y, lrelu(hb.y + bf2f((unsigned short)(me >> 16))));
        }
        if (r0 == r1) vm = make_float2(0.f, 0.f);
        *(float2*)(agg + (size_t)n * EMB + lane * 2) = vm;
    } else {
        if (lane < nc) {
            float vm = -__builtin_inff();
            for (int p = r0; p < r1; ++p) {
                int src = __builtin_amdgcn_readfirstlane(slot[p].x);
                float hb = h[(size_t)src * EMB + c0 + lane];
                float me = bf2f(emsg[(size_t)p * nc + lane]);
                vm = fmaxf(vm, lrelu(hb + me));
            }
            if (r0 == r1) vm = 0.f;
            agg[(size_t)n * EMB + c0 + lane] = vm;
        }
    }
}

// ---------------- small per-graph kernels (unchanged) ----------------
__global__ __launch_bounds__(128) void k_gb(const float* __restrict__ xg,
                                            const float* __restrict__ WaG,
                                            const float* __restrict__ ba,
                                            float* __restrict__ gb) {
    int g = blockIdx.x, c = threadIdx.x;
    __shared__ float row[EMB];
    row[c] = xg[(size_t)g * EMB + c];
    __syncthreads();
    float acc = ba[c];
#pragma unroll 8
    for (int k = 0; k < EMB; ++k) acc = fmaf(row[k], WaG[(size_t)k * EMB + c], acc);
    gb[(size_t)g * EMB + c] = acc;
}

__global__ __launch_bounds__(256) void k_gate(const float* __restrict__ x,
                                              const float* __restrict__ wg,
                                              const float* __restrict__ bg,
                                              float* __restrict__ gate, int N) {
    int n = blockIdx.x * 4 + (threadIdx.x >> 6);
    int lane = threadIdx.x & 63;
    if (n >= N) return;
    const float* xr = x + (size_t)n * EMB;
    float v = fmaf(xr[lane], wg[lane], xr[lane + 64] * wg[lane + 64]);
#pragma unroll
    for (int off = 32; off; off >>= 1) v += __shfl_xor(v, off, 64);
    if (lane == 0) gate[n] = v + bg[0];
}

__global__ __launch_bounds__(256) void k_gseg(const float* __restrict__ gate,
                                              const int* __restrict__ gstart,
                                              float* __restrict__ gmax,
                                              float* __restrict__ denom) {
    int g = blockIdx.x;
    int s0 = gstart[g], s1 = gstart[g + 1];
    __shared__ float red[256];
    int t = threadIdx.x;
    float mx = -__builtin_inff();
    for (int i = s0 + t; i < s1; i += 256) mx = fmaxf(mx, gate[i]);
    red[t] = mx;
    __syncthreads();
#pragma unroll
    for (int off = 128; off; off >>= 1) {
        if (t < off) red[t] = fmaxf(red[t], red[t + off]);
        __syncthreads();
    }
    float m = red[0];
    __syncthreads();
    float sum = 0.f;
    for (int i = s0 + t; i < s1; i += 256) sum += __expf(gate[i] - m);
    red[t] = sum;
    __syncthreads();
#pragma unroll
    for (int off = 128; off; off >>= 1) {
        if (t < off) red[t] += red[t + off];
        __syncthreads();
    }
    if (t == 0) {
        gmax[g] = (s1 > s0) ? m : 0.f;
        denom[g] = red[0];
    }
}

__global__ __launch_bounds__(512) void k_pool(const float* __restrict__ feat,
                                              const int* __restrict__ gstart,
                                              float* __restrict__ pooled) {
    int g = blockIdx.x;
    int c = threadIdx.x & 127;
    int r = threadIdx.x >> 7;
    int s0 = gstart[g], s1 = gstart[g + 1];
    float s = 0.f;
    for (int i = s0 + r; i < s1; i += 4) s += feat[(size_t)i * EMB + c];
    __shared__ float red[512];
    red[threadIdx.x] = s;
    __syncthreads();
    if (threadIdx.x < 256) red[threadIdx.x] += red[threadIdx.x + 256];
    __syncthreads();
    if (threadIdx.x < 128)
        pooled[(size_t)g * EMB + threadIdx.x] = red[threadIdx.x] + red[threadIdx.x + 128];
}

__global__ __launch_bounds__(128) void k_xg(const float* __restrict__ pooled,
                                            const float* __restrict__ xg,
                                            const float* __restrict__ Wt,
                                            const float* __restrict__ bt,
                                            float* __restrict__ xg_out) {
    int g = blockIdx.x, c = threadIdx.x;
    __shared__ float row[256];
    row[c] = pooled[(size_t)g * EMB + c];
    row[c + 128] = xg[(size_t)g * EMB + c];
    __syncthreads();
    float acc = bt[c];
#pragma unroll 8
    for (int k = 0; k < 256; ++k) acc = fmaf(row[k], Wt[(size_t)k * EMB + c], acc);
    xg_out[(size_t)g * EMB + c] = lrelu(acc) + row[c + 128];
}

// ---------------- launch ----------------
extern "C" void kernel_launch(void* const* d_in, const int* in_sizes, int n_in,
                              void* d_out, int out_size, void* d_ws, size_t ws_size,
                              hipStream_t stream) {
    const float* x0    = (const float*)d_in[0];
    const float* ea    = (const float*)d_in[1];
    const float* Wm    = (const float*)d_in[2];
    const float* bm    = (const float*)d_in[3];
    const float* Wa    = (const float*)d_in[4];
    const float* ba    = (const float*)d_in[5];
    const float* Wgate = (const float*)d_in[6];
    const float* bgate = (const float*)d_in[7];
    const float* Wfeat = (const float*)d_in[8];
    const float* bfeat = (const float*)d_in[9];
    const float* Wt    = (const float*)d_in[10];
    const float* bt    = (const float*)d_in[11];
    const int*   eidx  = (const int*)d_in[12];
    const int*   batch = (const int*)d_in[13];

    int N = in_sizes[0] / EMB;
    int E = in_sizes[1] / EDGE;
    int G = in_sizes[15];

    char* w = (char*)d_ws;
    auto alloc = [&](size_t bytes) {
        char* p = w;
        w += (bytes + 255) & ~(size_t)255;
        return p;
    };
    float* hbuf   = (float*)alloc((size_t)N * EMB * 4);   // h, later featbuf
    float* agg    = (float*)alloc((size_t)N * EMB * 4);
    float* gate   = (float*)alloc((size_t)N * 4);
    float* gb     = (float*)alloc((size_t)G * EMB * 4);
    float* pooled = (float*)alloc((size_t)G * EMB * 4);
    float* gmax   = (float*)alloc((size_t)G * 4);
    float* denom  = (float*)alloc((size_t)G * 4);
    float* xg_a   = (float*)alloc((size_t)G * EMB * 4);
    float* xg_b   = (float*)alloc((size_t)G * EMB * 4);
    int* deg      = (int*)alloc((size_t)N * 4);
    int* rowptr   = (int*)alloc((size_t)(N + 1) * 4);
    int* cursor   = (int*)alloc((size_t)N * 4);
    int2* slot    = (int2*)alloc((size_t)E * 8);
    int* gstart   = (int*)alloc((size_t)(G + 1) * 4);
    int* bsums    = (int*)alloc(1024 * 4);
    unsigned short* wpack = (unsigned short*)alloc((size_t)15 * 16384 * 2);

    // emsg buffer: column-chunked to fit remaining workspace (CH in {1,2,4})
    int ntiles = (E + 15) / 16;
    size_t remain = (w <= (char*)d_ws + ws_size) ? ((char*)d_ws + ws_size - w) : 0;
    int CH = 1;
    while (CH < 4 && (size_t)ntiles * 16 * (128 / CH) * 2 > remain) CH <<= 1;
    unsigned short* emsg = (unsigned short*)w;
    int nc = 128 / CH, nct = nc / 16;

    const int* esrc = eidx;
    const int* edst = eidx + E;
    int ebl = (E + 255) / 256;
    int NB  = (N + 255) / 256;

    hipMemsetAsync(deg, 0, (size_t)N * 4, stream);
    k_hist<<<ebl, 256, 0, stream>>>(edst, E, deg);
    k_scan1<<<NB, 256, 0, stream>>>(deg, N, rowptr, bsums);
    k_scan2<<<1, 256, 0, stream>>>(bsums, NB);
    k_scan3<<<NB, 256, 0, stream>>>(rowptr, bsums, N, E);
    hipMemcpyAsync(cursor, rowptr, (size_t)N * 4, hipMemcpyDeviceToDevice, stream);
    k_fill<<<ebl, 256, 0, stream>>>(esrc, edst, E, cursor, slot);
    k_gstart<<<(G + 256) / 256, 256, 0, stream>>>(batch, N, G, gstart);
    hipMemsetAsync(xg_a, 0, (size_t)G * EMB * 4, stream);
    k_wpack<<<960, 256, 0, stream>>>(Wm, Wa, Wfeat, wpack);

    int gemm_blocks = (N + 63) / 64;
    int gate_blocks = (N + 3) / 4;
    int aggl_blocks = (N + 3) / 4;
    int emsg_blocks = (ntiles + 3) / 4;

    const float* x_in = x0;
    float* xg_cur = xg_a;
    float* xg_nxt = xg_b;

    for (int s = 0; s < STEPS; ++s) {
        const unsigned short* wp = wpack + (size_t)s * 5 * 16384;
        // x updates in-place for s<2 (blocks touch disjoint 64-row tiles; harness
        // restores d_in before every launch); final step writes d_out.
        float* x_out = (s == STEPS - 1) ? (float*)d_out : (float*)x_in;

        k_gemm_bias<<<gemm_blocks, 256, 0, stream>>>(x_in, wp + 0 * 16384, bm + s * EMB,
                                                     hbuf, N);
        for (int ch = 0; ch < CH; ++ch) {
            k_emsg<<<emsg_blocks, 256, 0, stream>>>(ea, slot, wp + 1 * 16384, emsg,
                                                    E, ntiles, ch * nct, nct);
            k_aggl<<<aggl_blocks, 256, 0, stream>>>(hbuf, emsg, slot, rowptr, agg,
                                                    N, ch * nc, nc);
        }
        k_gb<<<G, 128, 0, stream>>>(xg_cur, Wa + (size_t)s * 384 * EMB + 128 * EMB,
                                    ba + s * EMB, gb);
        k_gemm_node<<<gemm_blocks, 256, 0, stream>>>(x_in, agg, wp + 2 * 16384,
                                                     wp + 3 * 16384, gb, batch, x_out, N);
        k_gate<<<gate_blocks, 256, 0, stream>>>(x_out, Wgate + s * EMB, bgate + s, gate, N);
        k_gseg<<<G, 256, 0, stream>>>(gate, gstart, gmax, denom);
        k_gemm_feat<<<gemm_blocks, 256, 0, stream>>>(x_out, wp + 4 * 16384, bfeat + s * EMB,
                                                     gate, gmax, denom, batch, hbuf, N);
        k_pool<<<G, 512, 0, stream>>>(hbuf, gstart, pooled);
        k_xg<<<G, 128, 0, stream>>>(pooled, xg_cur, Wt + (size_t)s * 256 * EMB,
                                    bt + s * EMB, xg_nxt);

        x_in = x_out;
        float* tmp = xg_cur; xg_cur = xg_nxt; xg_nxt = tmp;
    }

    hipMemcpyAsync((float*)d_out + (size_t)N * EMB, xg_cur, (size_t)G * EMB * 4,
                   hipMemcpyDeviceToDevice, stream);
}

// Round 5
// 754.440 us; speedup vs baseline: 1.8851x; 1.1406x over previous
//
#include <hip/hip_runtime.h>

#define EMB 128
#define EDGE 32
#define STEPS 3

typedef short bf8s __attribute__((ext_vector_type(8)));
typedef float f32x4 __attribute__((ext_vector_type(4)));
typedef unsigned short u16x4 __attribute__((ext_vector_type(4)));

__device__ __forceinline__ float lrelu(float v) { return v > 0.0f ? v : 0.01f * v; }
__device__ __forceinline__ unsigned short f2bf(float f) {
    unsigned u = __float_as_uint(f);
    u += 0x7fffu + ((u >> 16) & 1u);
    return (unsigned short)(u >> 16);
}
__device__ __forceinline__ float bf2f(unsigned short s) {
    return __uint_as_float(((unsigned)s) << 16);
}

// ---------------- CSR build ----------------
__global__ void k_hist(const int* __restrict__ dst, int E, int* __restrict__ deg) {
    int e = blockIdx.x * 256 + threadIdx.x;
    if (e < E) atomicAdd(&deg[dst[e]], 1);
}

__global__ void k_scan1(const int* __restrict__ deg, int N, int* __restrict__ rowptr,
                        int* __restrict__ bsums) {
    __shared__ int s[256];
    int t = threadIdx.x;
    int i = blockIdx.x * 256 + t;
    int v = (i < N) ? deg[i] : 0;
    s[t] = v;
    __syncthreads();
#pragma unroll
    for (int off = 1; off < 256; off <<= 1) {
        int x = (t >= off) ? s[t - off] : 0;
        __syncthreads();
        s[t] += x;
        __syncthreads();
    }
    if (i < N) rowptr[i] = s[t] - v;
    if (t == 255) bsums[blockIdx.x] = s[255];
}

__global__ void k_scan2(int* __restrict__ bsums, int NB) {
    __shared__ int s[256];
    __shared__ int carry;
    int t = threadIdx.x;
    if (t == 0) carry = 0;
    __syncthreads();
    for (int base = 0; base < NB; base += 256) {
        int i = base + t;
        int v = (i < NB) ? bsums[i] : 0;
        s[t] = v;
        __syncthreads();
#pragma unroll
        for (int off = 1; off < 256; off <<= 1) {
            int x = (t >= off) ? s[t - off] : 0;
            __syncthreads();
            s[t] += x;
            __syncthreads();
        }
        int excl = s[t] - v + carry;
        if (i < NB) bsums[i] = excl;
        int tot = s[255];
        __syncthreads();
        if (t == 0) carry += tot;
        __syncthreads();
    }
}

__global__ void k_scan3(int* __restrict__ rowptr, const int* __restrict__ bsums, int N, int E) {
    int i = blockIdx.x * 256 + threadIdx.x;
    if (i < N) rowptr[i] += bsums[i >> 8];
    if (i == 0) rowptr[N] = E;
}

__global__ void k_fill(const int* __restrict__ src, const int* __restrict__ dst, int E,
                       int* __restrict__ cursor, int2* __restrict__ slot) {
    int e = blockIdx.x * 256 + threadIdx.x;
    if (e < E) {
        int d = dst[e];
        int p = atomicAdd(&cursor[d], 1);
        slot[p] = make_int2(src[e], e);
    }
}

__global__ void k_gstart(const int* __restrict__ batch, int N, int G, int* __restrict__ gstart) {
    int g = blockIdx.x * blockDim.x + threadIdx.x;
    if (g > G) return;
    int lo = 0, hi = N;
    while (lo < hi) {
        int mid = (lo + hi) >> 1;
        if (batch[mid] < g) lo = mid + 1; else hi = mid;
    }
    gstart[g] = lo;
}

// ---------------- weight prepack: fp32 row-major -> bf16 B-fragment order ----------------
// B-frag (16x16x32): lane holds col n=lane&15, k=(lane>>4)*8+j.
// Per 128x128 unit: [kc(4)][ctile(8)][lane(64)][j(8)] = 16384 ushort.
// Units/step: 0=Wm_x 1=Wm_e(32 rows, kc=0 only) 2=Wa_x 3=Wa_agg 4=Wfeat.
__global__ __launch_bounds__(256) void k_wpack(const float* __restrict__ Wm,
                                               const float* __restrict__ Wa,
                                               const float* __restrict__ Wfeat,
                                               unsigned short* __restrict__ wpack) {
    int gid = blockIdx.x * 256 + threadIdx.x;
    int unit = gid >> 14;
    int e = gid & 16383;
    int s = unit / 5, u = unit % 5;
    const float* src; int rows;
    switch (u) {
        case 0: src = Wm + (size_t)s * 160 * EMB;             rows = 128; break;
        case 1: src = Wm + (size_t)s * 160 * EMB + 128 * EMB; rows = 32;  break;
        case 2: src = Wa + (size_t)s * 384 * EMB;             rows = 128; break;
        case 3: src = Wa + (size_t)s * 384 * EMB + 256 * EMB; rows = 128; break;
        default: src = Wfeat + (size_t)s * EMB * EMB;         rows = 128; break;
    }
    int k = e >> 7, n = e & 127;
    if (k >= rows) return;
    unsigned short b = f2bf(src[(size_t)k * EMB + n]);
    int kc = k >> 5, c = n >> 4, lane = (n & 15) | (((k & 31) >> 3) << 4), j = k & 7;
    wpack[(size_t)unit * 16384 + ((size_t)(kc * 8 + c) * 64 + lane) * 8 + j] = b;
}

// ---------------- MFMA GEMM core: 64 rows x 128 cols, K=128 ----------------
__device__ __forceinline__ void stageA(const float* __restrict__ A, int row0, int N,
                                       unsigned short* lA, int tid) {
#pragma unroll
    for (int i = 0; i < 8; ++i) {
        int idx = tid + i * 256;
        int m = idx >> 5, c4 = idx & 31, k0 = c4 * 4;
        float4 v = make_float4(0.f, 0.f, 0.f, 0.f);
        if (row0 + m < N) v = ((const float4*)(A + (size_t)(row0 + m) * EMB))[c4];
        int kc = k0 >> 5, oct = (k0 & 31) >> 3, j0 = k0 & 7;
        int lane = (m & 15) | (oct << 4), rt = m >> 4;
        u16x4 pk = { f2bf(v.x), f2bf(v.y), f2bf(v.z), f2bf(v.w) };
        *(u16x4*)&lA[(((kc * 4 + rt) * 64 + lane) * 8) + j0] = pk;
    }
}
// bf16 source variant (A already bf16, row-major 128 cols)
__device__ __forceinline__ void stageA_bf(const unsigned short* __restrict__ A, int row0, int N,
                                          unsigned short* lA, int tid) {
#pragma unroll
    for (int i = 0; i < 4; ++i) {
        int idx = tid + i * 256;          // 1024 int4 = 64x128 bf16
        int m = idx >> 4, o = idx & 15;   // o: which 8-col group (k0 = o*8)
        int4 v = make_int4(0, 0, 0, 0);
        if (row0 + m < N) v = ((const int4*)(A + (size_t)(row0 + m) * EMB))[o];
        int kc = o >> 2, oct = o & 3;
        int lane = (m & 15) | (oct << 4), rt = m >> 4;
        *(int4*)&lA[((kc * 4 + rt) * 64 + lane) * 8] = v;
    }
}
__device__ __forceinline__ void stageB(const unsigned short* __restrict__ Bp,
                                       unsigned short* lB, int tid) {
#pragma unroll
    for (int i = 0; i < 8; ++i) {
        int idx = tid + i * 256;
        ((int4*)lB)[idx] = ((const int4*)Bp)[idx];
    }
}
__device__ __forceinline__ void mfma128(const unsigned short* lA, const unsigned short* lB,
                                        f32x4 acc[8], int wv, int lane) {
#pragma unroll
    for (int kc = 0; kc < 4; ++kc) {
        bf8s a = *(const bf8s*)&lA[((kc * 4 + wv) * 64 + lane) * 8];
#pragma unroll
        for (int c = 0; c < 8; ++c) {
            bf8s b = *(const bf8s*)&lB[((kc * 8 + c) * 64 + lane) * 8];
            acc[c] = __builtin_amdgcn_mfma_f32_16x16x32_bf16(a, b, acc[c], 0, 0, 0);
        }
    }
}

// h16 = bf16(x @ Wm_x + bm)
__global__ __launch_bounds__(256) void k_gemm_bias(const float* __restrict__ A,
                                                   const unsigned short* __restrict__ Bp,
                                                   const float* __restrict__ bias,
                                                   unsigned short* __restrict__ C, int N) {
    __shared__ unsigned short lA[8192];
    __shared__ unsigned short lB[16384];
    int tid = threadIdx.x, wv = tid >> 6, lane = tid & 63;
    int row0 = blockIdx.x * 64;
    stageA(A, row0, N, lA, tid);
    stageB(Bp, lB, tid);
    __syncthreads();
    f32x4 acc[8];
#pragma unroll
    for (int c = 0; c < 8; ++c) acc[c] = (f32x4){0.f, 0.f, 0.f, 0.f};
    mfma128(lA, lB, acc, wv, lane);
    int li = lane & 15, quad = lane >> 4;
#pragma unroll
    for (int c = 0; c < 8; ++c) {
        int col = c * 16 + li;
        float b = bias[col];
#pragma unroll
        for (int rr = 0; rr < 4; ++rr) {
            int m = row0 + wv * 16 + quad * 4 + rr;
            if (m < N) C[(size_t)m * EMB + col] = f2bf(acc[c][rr] + b);
        }
    }
}

// x_out = lrelu(x@Wa_x + agg16@Wa_agg + gb[batch]) + x ; fused gate = x_out.wg + bg
__global__ __launch_bounds__(256) void k_gemm_node(const float* __restrict__ x,
                                                   const unsigned short* __restrict__ agg16,
                                                   const unsigned short* __restrict__ BpX,
                                                   const unsigned short* __restrict__ BpA,
                                                   const float* __restrict__ gb,
                                                   const int* __restrict__ batch,
                                                   float* __restrict__ xout,
                                                   const float* __restrict__ wg,
                                                   const float* __restrict__ bg,
                                                   float* __restrict__ gate, int N) {
    __shared__ unsigned short lA[8192];
    __shared__ unsigned short lB[16384];
    int tid = threadIdx.x, wv = tid >> 6, lane = tid & 63;
    int row0 = blockIdx.x * 64;
    stageA(x, row0, N, lA, tid);
    stageB(BpX, lB, tid);
    __syncthreads();
    f32x4 acc[8];
#pragma unroll
    for (int c = 0; c < 8; ++c) acc[c] = (f32x4){0.f, 0.f, 0.f, 0.f};
    mfma128(lA, lB, acc, wv, lane);
    __syncthreads();
    stageA_bf(agg16, row0, N, lA, tid);
    stageB(BpA, lB, tid);
    __syncthreads();
    mfma128(lA, lB, acc, wv, lane);
    int li = lane & 15, quad = lane >> 4;
    float gpart[4] = {0.f, 0.f, 0.f, 0.f};
#pragma unroll
    for (int c = 0; c < 8; ++c) {
        int col = c * 16 + li;
        float wgc = wg[col];
#pragma unroll
        for (int rr = 0; rr < 4; ++rr) {
            int m = row0 + wv * 16 + quad * 4 + rr;
            if (m < N) {
                int g = batch[m];
                float b = gb[(size_t)g * EMB + col];
                float res = x[(size_t)m * EMB + col];
                float v = lrelu(acc[c][rr] + b) + res;
                xout[(size_t)m * EMB + col] = v;
                gpart[rr] = fmaf(v, wgc, gpart[rr]);
            }
        }
    }
    // reduce gate partials over the 16 li-lanes of this quad
#pragma unroll
    for (int rr = 0; rr < 4; ++rr) {
#pragma unroll
        for (int off = 1; off < 16; off <<= 1)
            gpart[rr] += __shfl_xor(gpart[rr], off, 64);
    }
    if (li == 0) {
        float b0 = bg[0];
#pragma unroll
        for (int rr = 0; rr < 4; ++rr) {
            int m = row0 + wv * 16 + quad * 4 + rr;
            if (m < N) gate[m] = gpart[rr] + b0;
        }
    }
}

// feat16 = bf16(alpha * lrelu(x@Wfeat + bfeat))
__global__ __launch_bounds__(256) void k_gemm_feat(const float* __restrict__ A,
                                                   const unsigned short* __restrict__ Bp,
                                                   const float* __restrict__ bias,
                                                   const float* __restrict__ gate,
                                                   const float* __restrict__ gmax,
                                                   const float* __restrict__ denom,
                                                   const int* __restrict__ batch,
                                                   unsigned short* __restrict__ C, int N) {
    __shared__ unsigned short lA[8192];
    __shared__ unsigned short lB[16384];
    int tid = threadIdx.x, wv = tid >> 6, lane = tid & 63;
    int row0 = blockIdx.x * 64;
    stageA(A, row0, N, lA, tid);
    stageB(Bp, lB, tid);
    __syncthreads();
    f32x4 acc[8];
#pragma unroll
    for (int c = 0; c < 8; ++c) acc[c] = (f32x4){0.f, 0.f, 0.f, 0.f};
    mfma128(lA, lB, acc, wv, lane);
    int li = lane & 15, quad = lane >> 4;
    float alpha[4];
#pragma unroll
    for (int rr = 0; rr < 4; ++rr) {
        int m = row0 + wv * 16 + quad * 4 + rr;
        if (m < N) {
            int g = batch[m];
            alpha[rr] = __expf(gate[m] - gmax[g]) / denom[g];
        } else alpha[rr] = 0.f;
    }
#pragma unroll
    for (int c = 0; c < 8; ++c) {
        int col = c * 16 + li;
        float b = bias[col];
#pragma unroll
        for (int rr = 0; rr < 4; ++rr) {
            int m = row0 + wv * 16 + quad * 4 + rr;
            if (m < N) C[(size_t)m * EMB + col] = f2bf(alpha[rr] * lrelu(acc[c][rr] + b));
        }
    }
}

// ---------------- fused edge-message MFMA + segment-max ----------------
// One wave per node; 16-edge batches. A-frag: lane (li,oct) gathers
// ea[slot[r0+b+li].y][oct*8..+7]. 8 MFMAs vs LDS-staged Wm_e give emsg in
// C-layout (col=ci*16+li, row=oct*4+rr = edge b+oct*4+rr). Add h[src] (2B
// gather), lrelu, masked max; cross-quad shfl reduce; bf16 store.
__global__ __launch_bounds__(256) void k_fagg(const unsigned short* __restrict__ h,
                                              const float* __restrict__ ea,
                                              const int2* __restrict__ slot,
                                              const int* __restrict__ rowptr,
                                              const unsigned short* __restrict__ Bp,
                                              unsigned short* __restrict__ agg, int N) {
    __shared__ unsigned short lB[4096];   // Wm_e: [ctile(8)][lane(64)][j(8)]
    int tid = threadIdx.x;
    ((int4*)lB)[tid]       = ((const int4*)Bp)[tid];
    ((int4*)lB)[tid + 256] = ((const int4*)Bp)[tid + 256];
    __syncthreads();
    int wv = tid >> 6, lane = tid & 63;
    int n = blockIdx.x * 4 + wv;
    if (n >= N) return;
    int li = lane & 15, oct = lane >> 4;
    int r0 = rowptr[n], r1 = rowptr[n + 1], deg = r1 - r0;

    float vm[8];
#pragma unroll
    for (int ci = 0; ci < 8; ++ci) vm[ci] = -__builtin_inff();

    for (int b = 0; b < deg; b += 16) {
        int p = r0 + b + li;
        if (p > r1 - 1) p = r1 - 1;
        int2 sl = slot[p];
        // A fragment from this lane's edge (edge index b+li)
        const float4* ear = (const float4*)(ea + (size_t)sl.y * EDGE);
        float4 v0 = ear[oct * 2], v1 = ear[oct * 2 + 1];
        bf8s a;
        a[0] = (short)f2bf(v0.x); a[1] = (short)f2bf(v0.y);
        a[2] = (short)f2bf(v0.z); a[3] = (short)f2bf(v0.w);
        a[4] = (short)f2bf(v1.x); a[5] = (short)f2bf(v1.y);
        a[6] = (short)f2bf(v1.z); a[7] = (short)f2bf(v1.w);
        // src + validity for this lane's C rows (edges b+oct*4+rr)
        int src_r[4]; bool val_r[4];
#pragma unroll
        for (int rr = 0; rr < 4; ++rr) {
            src_r[rr] = __shfl(sl.x, oct * 4 + rr, 16);
            val_r[rr] = (b + oct * 4 + rr) < deg;
        }
#pragma unroll
        for (int ci = 0; ci < 8; ++ci) {
            bf8s bb = *(const bf8s*)&lB[(ci * 64 + lane) * 8];
            f32x4 acc = (f32x4){0.f, 0.f, 0.f, 0.f};
            acc = __builtin_amdgcn_mfma_f32_16x16x32_bf16(a, bb, acc, 0, 0, 0);
            int col = ci * 16 + li;
#pragma unroll
            for (int rr = 0; rr < 4; ++rr) {
                float hv = bf2f(h[(size_t)src_r[rr] * EMB + col]);
                float t = lrelu(hv + acc[rr]);
                if (val_r[rr]) vm[ci] = fmaxf(vm[ci], t);
            }
        }
    }
#pragma unroll
    for (int ci = 0; ci < 8; ++ci) {
        vm[ci] = fmaxf(vm[ci], __shfl_xor(vm[ci], 16, 64));
        vm[ci] = fmaxf(vm[ci], __shfl_xor(vm[ci], 32, 64));
    }
    float s0 = (oct == 0) ? vm[0] : (oct == 1) ? vm[1] : (oct == 2) ? vm[2] : vm[3];
    float s1 = (oct == 0) ? vm[4] : (oct == 1) ? vm[5] : (oct == 2) ? vm[6] : vm[7];
    if (deg == 0) { s0 = 0.f; s1 = 0.f; }
    agg[(size_t)n * EMB + oct * 16 + li]        = f2bf(s0);
    agg[(size_t)n * EMB + (oct + 4) * 16 + li]  = f2bf(s1);
}

// ---------------- small per-graph kernels ----------------
__global__ __launch_bounds__(128) void k_gb(const float* __restrict__ xg,
                                            const float* __restrict__ WaG,
                                            const float* __restrict__ ba,
                                            float* __restrict__ gb) {
    int g = blockIdx.x, c = threadIdx.x;
    __shared__ float row[EMB];
    row[c] = xg[(size_t)g * EMB + c];
    __syncthreads();
    float acc = ba[c];
#pragma unroll 8
    for (int k = 0; k < EMB; ++k) acc = fmaf(row[k], WaG[(size_t)k * EMB + c], acc);
    gb[(size_t)g * EMB + c] = acc;
}

__global__ __launch_bounds__(256) void k_gseg(const float* __restrict__ gate,
                                              const int* __restrict__ gstart,
                                              float* __restrict__ gmax,
                                              float* __restrict__ denom) {
    int g = blockIdx.x;
    int s0 = gstart[g], s1 = gstart[g + 1];
    __shared__ float red[256];
    int t = threadIdx.x;
    float mx = -__builtin_inff();
    for (int i = s0 + t; i < s1; i += 256) mx = fmaxf(mx, gate[i]);
    red[t] = mx;
    __syncthreads();
#pragma unroll
    for (int off = 128; off; off >>= 1) {
        if (t < off) red[t] = fmaxf(red[t], red[t + off]);
        __syncthreads();
    }
    float m = red[0];
    __syncthreads();
    float sum = 0.f;
    for (int i = s0 + t; i < s1; i += 256) sum += __expf(gate[i] - m);
    red[t] = sum;
    __syncthreads();
#pragma unroll
    for (int off = 128; off; off >>= 1) {
        if (t < off) red[t] += red[t + off];
        __syncthreads();
    }
    if (t == 0) {
        gmax[g] = (s1 > s0) ? m : 0.f;
        denom[g] = red[0];
    }
}

__global__ __launch_bounds__(512) void k_pool(const unsigned short* __restrict__ feat,
                                              const int* __restrict__ gstart,
                                              float* __restrict__ pooled) {
    int g = blockIdx.x;
    int c = threadIdx.x & 127;
    int r = threadIdx.x >> 7;
    int s0 = gstart[g], s1 = gstart[g + 1];
    float s = 0.f;
    for (int i = s0 + r; i < s1; i += 4) s += bf2f(feat[(size_t)i * EMB + c]);
    __shared__ float red[512];
    red[threadIdx.x] = s;
    __syncthreads();
    if (threadIdx.x < 256) red[threadIdx.x] += red[threadIdx.x + 256];
    __syncthreads();
    if (threadIdx.x < 128)
        pooled[(size_t)g * EMB + threadIdx.x] = red[threadIdx.x] + red[threadIdx.x + 128];
}

__global__ __launch_bounds__(128) void k_xg(const float* __restrict__ pooled,
                                            const float* __restrict__ xg,
                                            const float* __restrict__ Wt,
                                            const float* __restrict__ bt,
                                            float* __restrict__ xg_out) {
    int g = blockIdx.x, c = threadIdx.x;
    __shared__ float row[256];
    row[c] = pooled[(size_t)g * EMB + c];
    row[c + 128] = xg[(size_t)g * EMB + c];
    __syncthreads();
    float acc = bt[c];
#pragma unroll 8
    for (int k = 0; k < 256; ++k) acc = fmaf(row[k], Wt[(size_t)k * EMB + c], acc);
    xg_out[(size_t)g * EMB + c] = lrelu(acc) + row[c + 128];
}

// ---------------- launch ----------------
extern "C" void kernel_launch(void* const* d_in, const int* in_sizes, int n_in,
                              void* d_out, int out_size, void* d_ws, size_t ws_size,
                              hipStream_t stream) {
    const float* x0    = (const float*)d_in[0];
    const float* ea    = (const float*)d_in[1];
    const float* Wm    = (const float*)d_in[2];
    const float* bm    = (const float*)d_in[3];
    const float* Wa    = (const float*)d_in[4];
    const float* ba    = (const float*)d_in[5];
    const float* Wgate = (const float*)d_in[6];
    const float* bgate = (const float*)d_in[7];
    const float* Wfeat = (const float*)d_in[8];
    const float* bfeat = (const float*)d_in[9];
    const float* Wt    = (const float*)d_in[10];
    const float* bt    = (const float*)d_in[11];
    const int*   eidx  = (const int*)d_in[12];
    const int*   batch = (const int*)d_in[13];

    int N = in_sizes[0] / EMB;
    int E = in_sizes[1] / EDGE;
    int G = in_sizes[15];

    char* w = (char*)d_ws;
    auto alloc = [&](size_t bytes) {
        char* p = w;
        w += (bytes + 255) & ~(size_t)255;
        return p;
    };
    unsigned short* h16   = (unsigned short*)alloc((size_t)N * EMB * 2);
    unsigned short* agg16 = (unsigned short*)alloc((size_t)N * EMB * 2);
    unsigned short* ft16  = (unsigned short*)alloc((size_t)N * EMB * 2);
    float* gate   = (float*)alloc((size_t)N * 4);
    float* gb     = (float*)alloc((size_t)G * EMB * 4);
    float* pooled = (float*)alloc((size_t)G * EMB * 4);
    float* gmax   = (float*)alloc((size_t)G * 4);
    float* denom  = (float*)alloc((size_t)G * 4);
    float* xg_a   = (float*)alloc((size_t)G * EMB * 4);
    float* xg_b   = (float*)alloc((size_t)G * EMB * 4);
    int* deg      = (int*)alloc((size_t)N * 4);
    int* rowptr   = (int*)alloc((size_t)(N + 1) * 4);
    int* cursor   = (int*)alloc((size_t)N * 4);
    int2* slot    = (int2*)alloc((size_t)E * 8);
    int* gstart   = (int*)alloc((size_t)(G + 1) * 4);
    int* bsums    = (int*)alloc(1024 * 4);
    unsigned short* wpack = (unsigned short*)alloc((size_t)15 * 16384 * 2);

    const int* esrc = eidx;
    const int* edst = eidx + E;
    int ebl = (E + 255) / 256;
    int NB  = (N + 255) / 256;

    hipMemsetAsync(deg, 0, (size_t)N * 4, stream);
    k_hist<<<ebl, 256, 0, stream>>>(edst, E, deg);
    k_scan1<<<NB, 256, 0, stream>>>(deg, N, rowptr, bsums);
    k_scan2<<<1, 256, 0, stream>>>(bsums, NB);
    k_scan3<<<NB, 256, 0, stream>>>(rowptr, bsums, N, E);
    hipMemcpyAsync(cursor, rowptr, (size_t)N * 4, hipMemcpyDeviceToDevice, stream);
    k_fill<<<ebl, 256, 0, stream>>>(esrc, edst, E, cursor, slot);
    k_gstart<<<(G + 256) / 256, 256, 0, stream>>>(batch, N, G, gstart);
    hipMemsetAsync(xg_a, 0, (size_t)G * EMB * 4, stream);
    k_wpack<<<960, 256, 0, stream>>>(Wm, Wa, Wfeat, wpack);

    int gemm_blocks = (N + 63) / 64;
    int fagg_blocks = (N + 3) / 4;

    const float* x_in = x0;
    float* xg_cur = xg_a;
    float* xg_nxt = xg_b;

    for (int s = 0; s < STEPS; ++s) {
        const unsigned short* wp = wpack + (size_t)s * 5 * 16384;
        float* x_out = (s == STEPS - 1) ? (float*)d_out : (float*)x_in;

        k_gemm_bias<<<gemm_blocks, 256, 0, stream>>>(x_in, wp + 0 * 16384, bm + s * EMB,
                                                     h16, N);
        k_fagg<<<fagg_blocks, 256, 0, stream>>>(h16, ea, slot, rowptr, wp + 1 * 16384,
                                                agg16, N);
        k_gb<<<G, 128, 0, stream>>>(xg_cur, Wa + (size_t)s * 384 * EMB + 128 * EMB,
                                    ba + s * EMB, gb);
        k_gemm_node<<<gemm_blocks, 256, 0, stream>>>(x_in, agg16, wp + 2 * 16384,
                                                     wp + 3 * 16384, gb, batch, x_out,
                                                     Wgate + s * EMB, bgate + s, gate, N);
        k_gseg<<<G, 256, 0, stream>>>(gate, gstart, gmax, denom);
        k_gemm_feat<<<gemm_blocks, 256, 0, stream>>>(x_out, wp + 4 * 16384, bfeat + s * EMB,
                                                     gate, gmax, denom, batch, ft16, N);
        k_pool<<<G, 512, 0, stream>>>(ft16, gstart, pooled);
        k_xg<<<G, 128, 0, stream>>>(pooled, xg_cur, Wt + (size_t)s * 256 * EMB,
                                    bt + s * EMB, xg_nxt);

        x_in = x_out;
        float* tmp = xg_cur; xg_cur = xg_nxt; xg_nxt = tmp;
    }

    hipMemcpyAsync((float*)d_out + (size_t)N * EMB, xg_cur, (size_t)G * EMB * 4,
                   hipMemcpyDeviceToDevice, stream);
}